// Round 12
// baseline (115.137 us; speedup 1.0000x reference)
//
#include <hip/hip_runtime.h>
#include <cstdint>
#include <cstddef>

#define DIM 256
#define NSRC 8192
#define NCLS 64
#define KSTEPS 8          // K=256 / 32
#define INV_TAU (1.0f / 0.07f)
#define EPITCH 136        // epilogue LDS pitch (ushorts): 272B rows, 16B-aligned

typedef __attribute__((ext_vector_type(8))) short bf16x8;
typedef __attribute__((ext_vector_type(4))) float f32x4;
typedef unsigned char uchar;

// ---------------------------------------------------------------- helpers ---
__device__ __forceinline__ ushort f2bf_rne(float f) {
    uint u = __float_as_uint(f);
    uint r = u + 0x7fff + ((u >> 16) & 1);
    return (ushort)(r >> 16);
}
// order-preserving bf16 -> u16 ordinal (monotone increasing with value)
__device__ __forceinline__ uint bf2ord(uint u) {
    return u ^ (0x8000u + (u >> 15) * 0x7FFFu);
}
__device__ __forceinline__ float ord2f(uint o) {
    uint u = (o & 0x8000u) ? (o ^ 0x8000u) : (~o & 0xFFFFu);
    return __uint_as_float(u << 16);
}
__device__ __forceinline__ uint med3u(uint a, uint b, uint c) {
    uint d;
    asm("v_med3_u32 %0, %1, %2, %3" : "=v"(d) : "v"(a), "v"(b), "v"(c));
    return d;
}

__device__ __forceinline__ void gload_lds16(const void* g, void* l) {
    __builtin_amdgcn_global_load_lds((const __attribute__((address_space(1))) void*)g,
                                     (__attribute__((address_space(3))) void*)l,
                                     16, 0, 0);
}

// 8-deep sorted-union merge step with partner at xor-distance d (keys desc).
#define MERGESTEP(d)                                                               \
    {                                                                              \
        uint b0 = __shfl_xor(k0, d), b1 = __shfl_xor(k1, d), b2 = __shfl_xor(k2, d),\
             b3 = __shfl_xor(k3, d), b4 = __shfl_xor(k4, d), b5 = __shfl_xor(k5, d),\
             b6 = __shfl_xor(k6, d), b7 = __shfl_xor(k7, d);                        \
        uint r0 = max(k0, b0);                                                     \
        uint r1 = max(max(min(k0, b0), k1), b1);                                   \
        uint r2 = max(max(min(k0, b1), min(k1, b0)), max(k2, b2));                 \
        uint r3 = max(max(min(k0, b2), min(k1, b1)),                               \
                      max(max(min(k2, b0), k3), b3));                              \
        uint r4 = max(max(max(min(k0, b3), min(k1, b2)),                           \
                          max(min(k2, b1), min(k3, b0))), max(k4, b4));            \
        uint r5 = max(max(max(min(k0, b4), min(k1, b3)),                           \
                          max(min(k2, b2), min(k3, b1))),                          \
                      max(max(min(k4, b0), k5), b5));                              \
        uint r6 = max(max(max(min(k0, b5), min(k1, b4)),                           \
                          max(min(k2, b3), min(k3, b2))),                          \
                      max(max(min(k4, b1), min(k5, b0)), max(k6, b6)));            \
        uint r7 = max(max(max(min(k0, b6), min(k1, b5)),                           \
                          max(min(k2, b4), min(k3, b3))),                          \
                      max(max(min(k4, b2), min(k5, b1)),                           \
                          max(max(min(k6, b0), k7), b7)));                         \
        k0 = r0; k1 = r1; k2 = r2; k3 = r3; k4 = r4; k5 = r5; k6 = r6; k7 = r7;    \
    }

// ------------------------------------------------ l2norm -> bf16 (fused) ----
// one WAVE per row; waves [0, nA): A rows; [nA, nA+nB): B rows
__global__ __launch_bounds__(256) void l2bf2_k(const float* __restrict__ inA,
                                               ushort* __restrict__ outA, int nA,
                                               const float* __restrict__ inB,
                                               ushort* __restrict__ outB, int nB) {
    const int w = (blockIdx.x * 256 + threadIdx.x) >> 6;   // global wave id = row
    const int lane = threadIdx.x & 63;
    if (w >= nA + nB) return;
    const float* in;
    ushort* out;
    int row;
    if (w < nA) { in = inA; out = outA; row = w; }
    else        { in = inB; out = outB; row = w - nA; }
    float4 v = *(const float4*)(in + (size_t)row * DIM + lane * 4);
    float ss = v.x * v.x + v.y * v.y + v.z * v.z + v.w * v.w;
#pragma unroll
    for (int d = 1; d < 64; d <<= 1) ss += __shfl_xor(ss, d);
    const float n = fmaxf(sqrtf(ss), 1e-12f);
    ushort4 o;
    o.x = f2bf_rne(v.x / n);
    o.y = f2bf_rne(v.y / n);
    o.z = f2bf_rne(v.z / n);
    o.w = f2bf_rne(v.w / n);
    *(ushort4*)(out + (size_t)row * DIM + lane * 4) = o;
}

// ---------------- one-shot class build: lab8 + cstart + ordered clist -------
__global__ __launch_bounds__(256) void class_build_k(const int* __restrict__ labels,
                                                     uchar* __restrict__ lab8,
                                                     int* __restrict__ cstart,
                                                     int* __restrict__ clist, int n) {
    const int c = blockIdx.x, t = threadIdx.x;
    const int g = c * 256 + t;
    if (g < n) lab8[g] = (uchar)labels[g];

    __shared__ int sl[256], se[256];
    const int per = n >> 8;          // 32
    const int i0 = t * per;
    int less = 0, eq = 0;
    for (int j = 0; j < per; ++j) {
        const int l = labels[i0 + j];
        less += (l < c);
        eq += (l == c);
    }
    sl[t] = less; se[t] = eq;
    __syncthreads();
    for (int s = 1; s < 256; s <<= 1) {
        const int a = (t >= s) ? sl[t - s] : 0;
        const int b = (t >= s) ? se[t - s] : 0;
        __syncthreads();
        sl[t] += a; se[t] += b;
        __syncthreads();
    }
    const int base = sl[255];
    int pos = base + se[t] - eq;     // exclusive scan offset
    for (int j = 0; j < per; ++j) {
        const int i = i0 + j;
        if (labels[i] == c) clist[pos++] = i;
    }
    if (t == 0) cstart[c] = base;
    if (c == 0 && t == 1) cstart[NCLS] = n;
}

// ------------------------------------------------------------- MFMA GEMM ----
// C[M][N] (raw bf16) = A[M][256]*B[N][256]^T, 128x128 tile, 8 waves (512 thr).
// R9's proven K-loop (3-deep 48KB ring, one barrier/K-step, counted vmcnt,
// XCD-grouped mapping). NEW: after the C-stores, the 8 waves scan the LDS
// sim tile (4 lanes/row x 32 cols) building per-row EXACT top-8 ordinal-key
// chains + s1 partials, written to part_keys[row][64][8] / part_s1[row][64].
// This fills the K-loop's idle VALU slots (VALUBusy was 21%) and removes
// assign's 96MB HBM re-read. Exactness: any global-top-8 element of a row
// has <8 row elements above it, so it survives every sub-chain.
__global__ __launch_bounds__(512) void gemm_mfma_k(const ushort* __restrict__ A,
                                                   const ushort* __restrict__ B,
                                                   ushort* __restrict__ C,
                                                   uint* __restrict__ part_keys,
                                                   float* __restrict__ part_s1,
                                                   int M, int N) {
    __shared__ __align__(16) ushort smem[24576];   // 48 KB

    const int tid = threadIdx.x;
    const int lane = tid & 63, wid = tid >> 6;
    const int wr = wid >> 1, wc = wid & 1;        // 4x2 waves, 32x64 each

    // XCD-aware 2D-grouped mapping: grid 64(bn) x 48(bm), 3072 blocks, 8 XCDs.
    const int gx = gridDim.x;                      // 64
    const int bid = blockIdx.y * gx + blockIdx.x;
    const int rowsPerX = gridDim.y >> 3;           // 6
    const int grpW = 8;
    const int grpSize = rowsPerX * grpW;           // 48
    const int xcd = bid & 7;
    const int local = bid >> 3;                    // 0..383
    const int grp = local / grpSize;
    const int within = local % grpSize;
    const int bm = (xcd * rowsPerX + within % rowsPerX) * 128;
    const int bn = (grp * grpW + within / rowsPerX) * 128;

    // ---- staging: chunk id = tid (0..511), one 16B chunk per matrix ----
    const int cr = tid >> 2;               // tile row 0..127
    const int cch = tid & 3;               // chunk within 64B row-slice
    const int sch = cch ^ ((cr >> 1) & 3); // swizzled source chunk
    const char* aSrcP = (const char*)A + (size_t)(bm + cr) * (DIM * 2) + sch * 16;
    const char* bSrcP = (const char*)B + (size_t)(bn + cr) * (DIM * 2) + sch * 16;
    const uint ldsOff = (uint)(wid * 1024);        // wave-uniform base; +lane*16

    const int fr = lane & 15, fk = lane >> 4;
    const int swz = (fr >> 1) & 3;
    int idxA[2], idxB[4];
#pragma unroll
    for (int m = 0; m < 2; ++m)
        idxA[m] = (wr * 32 + m * 16 + fr) * 32 + ((fk ^ swz) * 8);
#pragma unroll
    for (int n = 0; n < 4; ++n)
        idxB[n] = (wc * 64 + n * 16 + fr) * 32 + ((fk ^ swz) * 8);

    f32x4 acc[2][4];
#pragma unroll
    for (int m = 0; m < 2; ++m)
#pragma unroll
        for (int n = 0; n < 4; ++n) acc[m][n] = (f32x4){0.f, 0.f, 0.f, 0.f};

    // 2 loads/thread per STAGE (A chunk, B chunk); slot b in 0..2
#define STAGE(b, ks)                                                               \
    {                                                                              \
        gload_lds16(aSrcP + (ks) * 64, (char*)smem + (b) * 8192 + ldsOff);         \
        gload_lds16(bSrcP + (ks) * 64, (char*)smem + 24576 + (b) * 8192 + ldsOff); \
    }

    // prologue: 2 stages in flight (4 outstanding loads/thread)
    STAGE(0, 0);
    STAGE(1, 1);

#pragma unroll
    for (int ks = 0; ks < KSTEPS; ++ks) {
        if (ks < KSTEPS - 1) { asm volatile("s_waitcnt vmcnt(2)" ::: "memory"); }
        else                 { asm volatile("s_waitcnt vmcnt(0)" ::: "memory"); }
        __builtin_amdgcn_s_barrier();          // all waves' stage-ks loads landed
        asm volatile("" ::: "memory");         // no LDS read hoists above barrier

        if (ks + 2 < KSTEPS) STAGE((ks + 2) % 3, ks + 2);  // refill ring slot

        const int slot = ks % 3;
        const ushort* sAc = smem + slot * 4096;
        const ushort* sBc = smem + 12288 + slot * 4096;
        bf16x8 av[2], bv[4];
#pragma unroll
        for (int m = 0; m < 2; ++m) av[m] = *(const bf16x8*)&sAc[idxA[m]];
#pragma unroll
        for (int n = 0; n < 4; ++n) bv[n] = *(const bf16x8*)&sBc[idxB[n]];
#pragma unroll
        for (int m = 0; m < 2; ++m)
#pragma unroll
            for (int n = 0; n < 4; ++n)
                acc[m][n] = __builtin_amdgcn_mfma_f32_16x16x32_bf16(av[m], bv[n], acc[m][n], 0, 0, 0);
    }
#undef STAGE

    // ---- epilogue: fragments -> raw bf16 LDS tile -> coalesced 16B stores --
    __syncthreads();
#pragma unroll
    for (int m = 0; m < 2; ++m) {
#pragma unroll
        for (int n = 0; n < 4; ++n) {
            const int colb = wc * 64 + n * 16 + fr;
#pragma unroll
            for (int j = 0; j < 4; ++j) {
                const int rowb = wr * 32 + m * 16 + fk * 4 + j;
                smem[rowb * EPITCH + colb] = f2bf_rne(acc[m][n][j]);
            }
        }
    }
    __syncthreads();
    {
        const int rr = tid >> 4, cc = (tid & 15) * 8;   // rr 0..31
#pragma unroll
        for (int it = 0; it < 4; ++it) {
            const int r = it * 32 + rr;
            uint4 v = *(const uint4*)&smem[r * EPITCH + cc];
            *(uint4*)(C + (size_t)(bm + r) * N + bn + cc) = v;
        }
    }

    // ---- in-block row scan: top-8 keys + s1 per (row, bn-block) ----------
    {
        const int rowL = wid * 16 + (lane >> 2);        // 0..127
        const int colb0 = (lane & 3) * 32;              // 0/32/64/96
        const int bnblk = bn >> 7;                      // 0..63
        const uint basekey = (uint)(8191 - bn - colb0); // idx part = basekey - cc
        uint k0 = 0, k1 = 0, k2 = 0, k3 = 0, k4 = 0, k5 = 0, k6 = 0, k7 = 0;
        float s1 = 0.f;
        const ushort* rp = &smem[rowL * EPITCH + colb0];
#pragma unroll
        for (int j = 0; j < 16; ++j) {
            const uint v = *(const uint*)(rp + 2 * j);
#pragma unroll
            for (int h = 0; h < 2; ++h) {
                const uint uu = (h == 0) ? (v & 0xFFFFu) : (v >> 16);
                s1 += __expf(fmaf(__uint_as_float(uu << 16), INV_TAU, -INV_TAU));
                const uint od = uu ^ (0x8000u + (uu >> 15) * 0x7FFFu);
                const uint nk = (od << 16) | (basekey - (uint)(2 * j + h));
                uint q1 = med3u(nk, k0, k1), q2 = med3u(nk, k1, k2),
                     q3 = med3u(nk, k2, k3), q4 = med3u(nk, k3, k4),
                     q5 = med3u(nk, k4, k5), q6 = med3u(nk, k5, k6),
                     q7 = med3u(nk, k6, k7);
                k0 = max(k0, nk);
                k1 = q1; k2 = q2; k3 = q3; k4 = q4; k5 = q5; k6 = q6; k7 = q7;
            }
        }
        // merge the 4 col-chunk lanes of this row (xor 1,2 stay in the group)
        s1 += __shfl_xor(s1, 1);
        s1 += __shfl_xor(s1, 2);
        MERGESTEP(1)
        MERGESTEP(2)
        if ((lane & 3) == 0) {
            const size_t pb = (size_t)(bm + rowL) * 64 + bnblk;
            uint4 lo; lo.x = k0; lo.y = k1; lo.z = k2; lo.w = k3;
            uint4 hi; hi.x = k4; hi.y = k5; hi.z = k6; hi.w = k7;
            *(uint4*)(part_keys + pb * 8) = lo;
            *(uint4*)(part_keys + pb * 8 + 4) = hi;
            part_s1[pb] = s1;
        }
    }
}

// ---------------- wave-per-target: merge partials + score -------------------
// part_keys[t][64][8]: each lane loads one block's sorted top-8; one 64-lane
// MERGE8 yields the EXACT global top-8 (val desc, idx asc). s1 from partials.
// nun rare fallback (negcnt<4) scans sim (raw bf16) + lab8 as before.
__global__ __launch_bounds__(256) void assign_score_w(const ushort* __restrict__ sim,
                                                      const uint* __restrict__ part_keys,
                                                      const float* __restrict__ part_s1,
                                                      const int* __restrict__ labels,
                                                      const uchar* __restrict__ lab8,
                                                      const int* __restrict__ cstart,
                                                      const int* __restrict__ clist,
                                                      float* __restrict__ scores_out,
                                                      float* __restrict__ logt_out) {
    const int lane = threadIdx.x & 63, wid = threadIdx.x >> 6;
    const int t = blockIdx.x * 4 + wid;
    const ushort* row = sim + (size_t)t * NSRC;

    // each lane: one bn-block's sorted top-8
    const uint* pk = part_keys + ((size_t)t * 64 + lane) * 8;
    uint4 lo = *(const uint4*)pk;
    uint4 hi = *(const uint4*)(pk + 4);
    uint k0 = lo.x, k1 = lo.y, k2 = lo.z, k3 = lo.w;
    uint k4 = hi.x, k5 = hi.y, k6 = hi.z, k7 = hi.w;
#pragma unroll
    for (int d = 1; d < 64; d <<= 1) MERGESTEP(d)

    // s1 from partials
    float s1 = part_s1[(size_t)t * 64 + lane];
#pragma unroll
    for (int d = 1; d < 64; d <<= 1) s1 += __shfl_xor(s1, d);

    // ---- labels of top-8 ----
    const int l0 = labels[8191 - (int)(k0 & 0xFFFF)];
    const int l1 = labels[8191 - (int)(k1 & 0xFFFF)];
    const int l2 = labels[8191 - (int)(k2 & 0xFFFF)];
    const int l3 = labels[8191 - (int)(k3 & 0xFFFF)];
    const int l4 = labels[8191 - (int)(k4 & 0xFFFF)];
    const int l5 = labels[8191 - (int)(k5 & 0xFFFF)];
    const int l6 = labels[8191 - (int)(k6 & 0xFFFF)];
    const int l7 = labels[8191 - (int)(k7 & 0xFFFF)];

    // ---- assigned = min label among modes of top-5 labels ----
    const int c0 = 1 + (l0 == l1) + (l0 == l2) + (l0 == l3) + (l0 == l4);
    const int c1 = (l1 == l0) + 1 + (l1 == l2) + (l1 == l3) + (l1 == l4);
    const int c2 = (l2 == l0) + (l2 == l1) + 1 + (l2 == l3) + (l2 == l4);
    const int c3 = (l3 == l0) + (l3 == l1) + (l3 == l2) + 1 + (l3 == l4);
    const int c4 = (l4 == l0) + (l4 == l1) + (l4 == l2) + (l4 == l3) + 1;
    const int maxc = max(max(max(c0, c1), max(c2, c3)), c4);
    int assigned = 0x7fffffff;
    if (c0 == maxc) assigned = min(assigned, l0);
    if (c1 == maxc) assigned = min(assigned, l1);
    if (c2 == maxc) assigned = min(assigned, l2);
    if (c3 == maxc) assigned = min(assigned, l3);
    if (c4 == maxc) assigned = min(assigned, l4);
    const int aL = assigned;

    // ---- nun: first-4 negatives (exact if <=4 positives in top-8) ----
    const int negcnt = (l0 != aL) + (l1 != aL) + (l2 != aL) + (l3 != aL) +
                       (l4 != aL) + (l5 != aL) + (l6 != aL) + (l7 != aL);
    float nun = 0.f;
    if (negcnt >= 4) {
        int c = 0;
#define NSTEP(kj, lj)                                                       \
        {                                                                   \
            bool take = ((lj) != aL) && (c < 4);                            \
            nun += take ? ord2f((kj) >> 16) : 0.f;                          \
            c += take ? 1 : 0;                                              \
        }
        NSTEP(k0, l0) NSTEP(k1, l1) NSTEP(k2, l2) NSTEP(k3, l3)
        NSTEP(k4, l4) NSTEP(k5, l5) NSTEP(k6, l6) NSTEP(k7, l7)
#undef NSTEP
    } else {
        // rare fallback: full-row top-4 negative chain in ord domain
        uint n0 = 0, n1 = 0, n2 = 0, n3 = 0;
        for (int i0 = lane * 8; i0 < NSRC; i0 += 512) {
            uint4 w = *(const uint4*)(row + i0);
            uint2 lw = *(const uint2*)(lab8 + i0);
#define NEGP(u16, lb)                                                       \
            {                                                               \
                uint uu = (uint)(u16);                                      \
                uint od = uu ^ (0x8000u + (uu >> 15) * 0x7FFFu);            \
                uint x = ((lb) == aL) ? 0u : od;                            \
                uint q1 = med3u(x, n0, n1);                                 \
                uint q2 = med3u(x, n1, n2);                                 \
                uint q3 = med3u(x, n2, n3);                                 \
                n0 = max(n0, x); n1 = q1; n2 = q2; n3 = q3;                 \
            }
            NEGP(w.x & 0xFFFF, (int)(lw.x & 255));
            NEGP(w.x >> 16,    (int)((lw.x >> 8) & 255));
            NEGP(w.y & 0xFFFF, (int)((lw.x >> 16) & 255));
            NEGP(w.y >> 16,    (int)(lw.x >> 24));
            NEGP(w.z & 0xFFFF, (int)(lw.y & 255));
            NEGP(w.z >> 16,    (int)((lw.y >> 8) & 255));
            NEGP(w.w & 0xFFFF, (int)((lw.y >> 16) & 255));
            NEGP(w.w >> 16,    (int)(lw.y >> 24));
#undef NEGP
        }
#pragma unroll
        for (int d = 1; d < 64; d <<= 1) {
            uint b0 = __shfl_xor(n0, d), b1 = __shfl_xor(n1, d),
                 b2 = __shfl_xor(n2, d), b3 = __shfl_xor(n3, d);
            uint r0 = max(n0, b0);
            uint r1 = max(max(min(n0, b0), n1), b1);
            uint r2 = max(max(min(n0, b1), min(n1, b0)), max(n2, b2));
            uint r3 = max(max(min(n0, b2), min(n1, b1)),
                          max(max(min(n2, b0), n3), b3));
            n0 = r0; n1 = r1; n2 = r2; n3 = r3;
        }
        nun = (n0 ? ord2f(n0) : 0.f) + (n1 ? ord2f(n1) : 0.f) +
              (n2 ? ord2f(n2) : 0.f) + (n3 ? ord2f(n3) : 0.f);
    }

    // ---- class-member scan: top-4 positives + sp (gathered, ~128 elems) ----
    const int cs = cstart[aL], ce = cstart[aL + 1];
    float tp0 = -2.f, tp1 = -2.f, tp2 = -2.f, tp3 = -2.f;
    float sp = 0.f;
    for (int p = cs + lane; p < ce; p += 64) {
        const int idx = clist[p];
        float v = __uint_as_float(((uint)row[idx]) << 16);   // raw bf16 -> f32
        sp += __expf(fmaf(v, INV_TAU, -INV_TAU));
        float q1 = __builtin_amdgcn_fmed3f(v, tp0, tp1);
        float q2 = __builtin_amdgcn_fmed3f(v, tp1, tp2);
        float q3 = __builtin_amdgcn_fmed3f(v, tp2, tp3);
        tp0 = fmaxf(tp0, v); tp1 = q1; tp2 = q2; tp3 = q3;
    }
#pragma unroll
    for (int d = 1; d < 64; d <<= 1) {
        sp += __shfl_xor(sp, d);
        float b0 = __shfl_xor(tp0, d), b1 = __shfl_xor(tp1, d),
              b2 = __shfl_xor(tp2, d), b3 = __shfl_xor(tp3, d);
        float r0 = fmaxf(tp0, b0);
        float r1 = fmaxf(fmaxf(fminf(tp0, b0), tp1), b1);
        float r2 = fmaxf(fmaxf(fminf(tp0, b1), fminf(tp1, b0)), fmaxf(tp2, b2));
        float r3 = fmaxf(fmaxf(fminf(tp0, b2), fminf(tp1, b1)),
                         fmaxf(fmaxf(fminf(tp2, b0), tp3), b3));
        tp0 = r0; tp1 = r1; tp2 = r2; tp3 = r3;
    }

    if (lane == 0) {
        float nln = (tp0 > -1.5f ? tp0 : 0.f) + (tp1 > -1.5f ? tp1 : 0.f) +
                    (tp2 > -1.5f ? tp2 : 0.f) + (tp3 > -1.5f ? tp3 : 0.f);
        scores_out[t] = nln / nun;
        logt_out[t] = logf(sp / s1 + 1e-6f);
    }
}

// --------------------------------------- wave-per-element rank selection ----
__global__ __launch_bounds__(256) void select_topk_w(const float* __restrict__ scores,
                                                     int* __restrict__ selected,
                                                     int n, int k) {
    const int lane = threadIdx.x & 63, wid = threadIdx.x >> 6;
    const int t = blockIdx.x * 4 + wid;
    if (t >= n) return;
    const float st = scores[t];
    int rank = 0;
    for (int j0 = lane * 4; j0 < n; j0 += 256) {
        float4 v = *(const float4*)(scores + j0);
        rank += (v.x > st) || (v.x == st && (j0 + 0) < t);
        rank += (v.y > st) || (v.y == st && (j0 + 1) < t);
        rank += (v.z > st) || (v.z == st && (j0 + 2) < t);
        rank += (v.w > st) || (v.w == st && (j0 + 3) < t);
    }
    for (int d = 1; d < 64; d <<= 1) rank += __shfl_xor(rank, d);
    if (lane == 0) selected[t] = (rank < k) ? 1 : 0;
}

// ----------------------------------------------------------- finalize -------
__global__ __launch_bounds__(256) void finalize_k(const float* __restrict__ logt,
                                                  const int* __restrict__ selected,
                                                  float* __restrict__ out, int n, int k) {
    __shared__ float red[256];
    const int tid = threadIdx.x;
    float s = 0.f;
    for (int i = tid; i < n; i += 256) s += selected[i] ? logt[i] : 0.f;
    red[tid] = s;
    __syncthreads();
    for (int st = 128; st > 0; st >>= 1) {
        if (tid < st) red[tid] += red[tid + st];
        __syncthreads();
    }
    if (tid == 0) out[0] = -red[0] / (float)k;
}

// -------------------------------------------------------------- launch ------
extern "C" void kernel_launch(void* const* d_in, const int* in_sizes, int n_in,
                              void* d_out, int out_size, void* d_ws, size_t ws_size,
                              hipStream_t stream) {
    const float* srcF = (const float*)d_in[0];
    const int* labels = (const int*)d_in[1];
    const float* tgtF = (const float*)d_in[2];
    float* out = (float*)d_out;

    const int n_src = in_sizes[1];            // 8192
    const int d = in_sizes[0] / n_src;        // 256
    const int n_tgt = in_sizes[2] / d;        // 6144
    const int topn = n_tgt * 2 / 3;           // 4096

    char* ws = (char*)d_ws;
    ushort* src2 = (ushort*)ws;  ws += (size_t)n_src * DIM * sizeof(ushort);
    ushort* tgt2 = (ushort*)ws;  ws += (size_t)n_tgt * DIM * sizeof(ushort);
    ushort* sim  = (ushort*)ws;  ws += (size_t)n_tgt * NSRC * sizeof(ushort);
    float* scores = (float*)ws;  ws += (size_t)n_tgt * sizeof(float);
    float* logt   = (float*)ws;  ws += (size_t)n_tgt * sizeof(float);
    int* selected = (int*)ws;    ws += (size_t)n_tgt * sizeof(int);
    int* cstart   = (int*)ws;    ws += (size_t)(NCLS + 1) * sizeof(int);
    int* clist    = (int*)ws;    ws += (size_t)n_src * sizeof(int);
    uchar* lab8   = (uchar*)ws;  ws += (size_t)n_src;
    ws = (char*)(((uintptr_t)ws + 255) & ~(uintptr_t)255);
    uint* part_keys = (uint*)ws; ws += (size_t)n_tgt * 64 * 8 * sizeof(uint);
    float* part_s1  = (float*)ws; ws += (size_t)n_tgt * 64 * sizeof(float);

    const int nrows = n_tgt + n_src;          // one wave per row, 4 waves/block
    l2bf2_k<<<(nrows + 3) / 4, 256, 0, stream>>>(tgtF, tgt2, n_tgt, srcF, src2, n_src);
    class_build_k<<<NCLS, 256, 0, stream>>>(labels, lab8, cstart, clist, n_src);

    dim3 grid(n_src / 128, n_tgt / 128);      // 64 x 48 = 3072 blocks
    gemm_mfma_k<<<grid, 512, 0, stream>>>(tgt2, src2, sim, part_keys, part_s1,
                                          n_tgt, n_src);

    assign_score_w<<<n_tgt / 4, 256, 0, stream>>>(sim, part_keys, part_s1, labels,
                                                  lab8, cstart, clist, scores, logt);
    select_topk_w<<<(n_tgt + 3) / 4, 256, 0, stream>>>(scores, selected, n_tgt, topn);
    finalize_k<<<1, 256, 0, stream>>>(logt, selected, out, n_tgt, topn);
}

// Round 13
// 115.128 us; speedup vs baseline: 1.0001x; 1.0001x over previous
//
#include <hip/hip_runtime.h>
#include <cstdint>
#include <cstddef>

#define DIM 256
#define NSRC 8192
#define NCLS 64
#define KSTEPS 8          // K=256 / 32
#define INV_TAU (1.0f / 0.07f)
#define EPITCH 136        // epilogue LDS pitch (ushorts): 272B rows, 16B-aligned

typedef __attribute__((ext_vector_type(8))) short bf16x8;
typedef __attribute__((ext_vector_type(4))) float f32x4;
typedef unsigned char uchar;

// ---------------------------------------------------------------- helpers ---
__device__ __forceinline__ ushort f2bf_rne(float f) {
    uint u = __float_as_uint(f);
    uint r = u + 0x7fff + ((u >> 16) & 1);
    return (ushort)(r >> 16);
}
// order-preserving bf16 -> u16 ordinal (monotone increasing with value)
__device__ __forceinline__ uint bf2ord(uint u) {
    return u ^ (0x8000u + (u >> 15) * 0x7FFFu);
}
__device__ __forceinline__ float ord2f(uint o) {
    uint u = (o & 0x8000u) ? (o ^ 0x8000u) : (~o & 0xFFFFu);
    return __uint_as_float(u << 16);
}
__device__ __forceinline__ uint med3u(uint a, uint b, uint c) {
    uint d;
    asm("v_med3_u32 %0, %1, %2, %3" : "=v"(d) : "v"(a), "v"(b), "v"(c));
    return d;
}

__device__ __forceinline__ void gload_lds16(const void* g, void* l) {
    __builtin_amdgcn_global_load_lds((const __attribute__((address_space(1))) void*)g,
                                     (__attribute__((address_space(3))) void*)l,
                                     16, 0, 0);
}

// 8-deep sorted-union merge with values b0..b7 already in registers.
#define MERGEVALS                                                                  \
    {                                                                              \
        uint r0 = max(k0, b0);                                                     \
        uint r1 = max(max(min(k0, b0), k1), b1);                                   \
        uint r2 = max(max(min(k0, b1), min(k1, b0)), max(k2, b2));                 \
        uint r3 = max(max(min(k0, b2), min(k1, b1)),                               \
                      max(max(min(k2, b0), k3), b3));                              \
        uint r4 = max(max(max(min(k0, b3), min(k1, b2)),                           \
                          max(min(k2, b1), min(k3, b0))), max(k4, b4));            \
        uint r5 = max(max(max(min(k0, b4), min(k1, b3)),                           \
                          max(min(k2, b2), min(k3, b1))),                          \
                      max(max(min(k4, b0), k5), b5));                              \
        uint r6 = max(max(max(min(k0, b5), min(k1, b4)),                           \
                          max(min(k2, b3), min(k3, b2))),                          \
                      max(max(min(k4, b1), min(k5, b0)), max(k6, b6)));            \
        uint r7 = max(max(max(min(k0, b6), min(k1, b5)),                           \
                          max(min(k2, b4), min(k3, b3))),                          \
                      max(max(min(k4, b2), min(k5, b1)),                           \
                          max(max(min(k6, b0), k7), b7)));                         \
        k0 = r0; k1 = r1; k2 = r2; k3 = r3; k4 = r4; k5 = r5; k6 = r6; k7 = r7;    \
    }
#define MERGESTEP(d)                                                               \
    {                                                                              \
        uint b0 = __shfl_xor(k0, d), b1 = __shfl_xor(k1, d), b2 = __shfl_xor(k2, d),\
             b3 = __shfl_xor(k3, d), b4 = __shfl_xor(k4, d), b5 = __shfl_xor(k5, d),\
             b6 = __shfl_xor(k6, d), b7 = __shfl_xor(k7, d);                        \
        MERGEVALS                                                                  \
    }

// ------------------------------------------------ l2norm -> bf16 (fused) ----
// one WAVE per row; waves [0, nA): A rows; [nA, nA+nB): B rows
__global__ __launch_bounds__(256) void l2bf2_k(const float* __restrict__ inA,
                                               ushort* __restrict__ outA, int nA,
                                               const float* __restrict__ inB,
                                               ushort* __restrict__ outB, int nB) {
    const int w = (blockIdx.x * 256 + threadIdx.x) >> 6;   // global wave id = row
    const int lane = threadIdx.x & 63;
    if (w >= nA + nB) return;
    const float* in;
    ushort* out;
    int row;
    if (w < nA) { in = inA; out = outA; row = w; }
    else        { in = inB; out = outB; row = w - nA; }
    float4 v = *(const float4*)(in + (size_t)row * DIM + lane * 4);
    float ss = v.x * v.x + v.y * v.y + v.z * v.z + v.w * v.w;
#pragma unroll
    for (int d = 1; d < 64; d <<= 1) ss += __shfl_xor(ss, d);
    const float n = fmaxf(sqrtf(ss), 1e-12f);
    ushort4 o;
    o.x = f2bf_rne(v.x / n);
    o.y = f2bf_rne(v.y / n);
    o.z = f2bf_rne(v.z / n);
    o.w = f2bf_rne(v.w / n);
    *(ushort4*)(out + (size_t)row * DIM + lane * 4) = o;
}

// ---------------- one-shot class build: lab8 + cstart + ordered clist -------
__global__ __launch_bounds__(256) void class_build_k(const int* __restrict__ labels,
                                                     uchar* __restrict__ lab8,
                                                     int* __restrict__ cstart,
                                                     int* __restrict__ clist, int n) {
    const int c = blockIdx.x, t = threadIdx.x;
    const int g = c * 256 + t;
    if (g < n) lab8[g] = (uchar)labels[g];

    __shared__ int sl[256], se[256];
    const int per = n >> 8;          // 32
    const int i0 = t * per;
    int less = 0, eq = 0;
    for (int j = 0; j < per; ++j) {
        const int l = labels[i0 + j];
        less += (l < c);
        eq += (l == c);
    }
    sl[t] = less; se[t] = eq;
    __syncthreads();
    for (int s = 1; s < 256; s <<= 1) {
        const int a = (t >= s) ? sl[t - s] : 0;
        const int b = (t >= s) ? se[t - s] : 0;
        __syncthreads();
        sl[t] += a; se[t] += b;
        __syncthreads();
    }
    const int base = sl[255];
    int pos = base + se[t] - eq;     // exclusive scan offset
    for (int j = 0; j < per; ++j) {
        const int i = i0 + j;
        if (labels[i] == c) clist[pos++] = i;
    }
    if (t == 0) cstart[c] = base;
    if (c == 0 && t == 1) cstart[NCLS] = n;
}

// ------------------------------------------------------------- MFMA GEMM ----
// C[M][N] (raw bf16) = A[M][256]*B[N][256]^T, 128x128 tile, 8 waves (512 thr).
// R9 EXACT (measured best, 40.4us): 3-deep 48KB ring + raw s_barrier +
// counted vmcnt + XCD-grouped mapping; each wave 32x64 (acc 2x4).
__global__ __launch_bounds__(512) void gemm_mfma_k(const ushort* __restrict__ A,
                                                   const ushort* __restrict__ B,
                                                   ushort* __restrict__ C,
                                                   int M, int N) {
    __shared__ __align__(16) ushort smem[24576];   // 48 KB

    const int tid = threadIdx.x;
    const int lane = tid & 63, wid = tid >> 6;
    const int wr = wid >> 1, wc = wid & 1;        // 4x2 waves, 32x64 each

    // XCD-aware 2D-grouped mapping: grid 64(bn) x 48(bm), 3072 blocks, 8 XCDs.
    const int gx = gridDim.x;                      // 64
    const int bid = blockIdx.y * gx + blockIdx.x;
    const int rowsPerX = gridDim.y >> 3;           // 6
    const int grpW = 8;
    const int grpSize = rowsPerX * grpW;           // 48
    const int xcd = bid & 7;
    const int local = bid >> 3;                    // 0..383
    const int grp = local / grpSize;
    const int within = local % grpSize;
    const int bm = (xcd * rowsPerX + within % rowsPerX) * 128;
    const int bn = (grp * grpW + within / rowsPerX) * 128;

    // ---- staging: chunk id = tid (0..511), one 16B chunk per matrix ----
    const int cr = tid >> 2;               // tile row 0..127
    const int cch = tid & 3;               // chunk within 64B row-slice
    const int sch = cch ^ ((cr >> 1) & 3); // swizzled source chunk
    const char* aSrcP = (const char*)A + (size_t)(bm + cr) * (DIM * 2) + sch * 16;
    const char* bSrcP = (const char*)B + (size_t)(bn + cr) * (DIM * 2) + sch * 16;
    const uint ldsOff = (uint)(wid * 1024);        // wave-uniform base; +lane*16

    const int fr = lane & 15, fk = lane >> 4;
    const int swz = (fr >> 1) & 3;
    int idxA[2], idxB[4];
#pragma unroll
    for (int m = 0; m < 2; ++m)
        idxA[m] = (wr * 32 + m * 16 + fr) * 32 + ((fk ^ swz) * 8);
#pragma unroll
    for (int n = 0; n < 4; ++n)
        idxB[n] = (wc * 64 + n * 16 + fr) * 32 + ((fk ^ swz) * 8);

    f32x4 acc[2][4];
#pragma unroll
    for (int m = 0; m < 2; ++m)
#pragma unroll
        for (int n = 0; n < 4; ++n) acc[m][n] = (f32x4){0.f, 0.f, 0.f, 0.f};

    // 2 loads/thread per STAGE (A chunk, B chunk); slot b in 0..2
#define STAGE(b, ks)                                                               \
    {                                                                              \
        gload_lds16(aSrcP + (ks) * 64, (char*)smem + (b) * 8192 + ldsOff);         \
        gload_lds16(bSrcP + (ks) * 64, (char*)smem + 24576 + (b) * 8192 + ldsOff); \
    }

    // prologue: 2 stages in flight (4 outstanding loads/thread)
    STAGE(0, 0);
    STAGE(1, 1);

#pragma unroll
    for (int ks = 0; ks < KSTEPS; ++ks) {
        if (ks < KSTEPS - 1) { asm volatile("s_waitcnt vmcnt(2)" ::: "memory"); }
        else                 { asm volatile("s_waitcnt vmcnt(0)" ::: "memory"); }
        __builtin_amdgcn_s_barrier();          // all waves' stage-ks loads landed
        asm volatile("" ::: "memory");         // no LDS read hoists above barrier

        if (ks + 2 < KSTEPS) STAGE((ks + 2) % 3, ks + 2);  // refill ring slot

        const int slot = ks % 3;
        const ushort* sAc = smem + slot * 4096;
        const ushort* sBc = smem + 12288 + slot * 4096;
        bf16x8 av[2], bv[4];
#pragma unroll
        for (int m = 0; m < 2; ++m) av[m] = *(const bf16x8*)&sAc[idxA[m]];
#pragma unroll
        for (int n = 0; n < 4; ++n) bv[n] = *(const bf16x8*)&sBc[idxB[n]];
#pragma unroll
        for (int m = 0; m < 2; ++m)
#pragma unroll
            for (int n = 0; n < 4; ++n)
                acc[m][n] = __builtin_amdgcn_mfma_f32_16x16x32_bf16(av[m], bv[n], acc[m][n], 0, 0, 0);
    }
#undef STAGE

    // ---- epilogue: fragments -> raw bf16 LDS tile -> coalesced 16B stores --
    __syncthreads();
#pragma unroll
    for (int m = 0; m < 2; ++m) {
#pragma unroll
        for (int n = 0; n < 4; ++n) {
            const int colb = wc * 64 + n * 16 + fr;
#pragma unroll
            for (int j = 0; j < 4; ++j) {
                const int rowb = wr * 32 + m * 16 + fk * 4 + j;
                smem[rowb * EPITCH + colb] = f2bf_rne(acc[m][n][j]);
            }
        }
    }
    __syncthreads();
    const int rr = tid >> 4, cc = (tid & 15) * 8;   // rr 0..31
#pragma unroll
    for (int it = 0; it < 4; ++it) {
        const int r = it * 32 + rr;
        uint4 v = *(const uint4*)&smem[r * EPITCH + cc];
        *(uint4*)(C + (size_t)(bm + r) * N + bn + cc) = v;
    }
}

// ---------------- 2-waves-per-target: half-row dual-chain + LDS merge -------
// sim holds RAW bf16. Block = 512 thr (8 waves) = 4 targets x 2 waves.
// Each wave scans its 4096-elem half with dual depth-4 chains + exact-detect
// (+ per-half CH8 fallback); the two sorted-8s + s1 merge via LDS. Half-1
// waves retire after the barrier; half-0 waves do labels/mode/nun/class.
__global__ __launch_bounds__(512) void assign_score_w(const ushort* __restrict__ sim,
                                                      const int* __restrict__ labels,
                                                      const uchar* __restrict__ lab8,
                                                      const int* __restrict__ cstart,
                                                      const int* __restrict__ clist,
                                                      float* __restrict__ scores_out,
                                                      float* __restrict__ logt_out) {
    const int lane = threadIdx.x & 63, wid = threadIdx.x >> 6;
    const int slot = wid >> 1;        // target slot 0..3
    const int half = wid & 1;         // which 4096-half this wave owns
    const int t = blockIdx.x * 4 + slot;
    const ushort* row = sim + (size_t)t * NSRC;
    const int base = half * 4096;

    __shared__ uint mk[8][8];
    __shared__ float ms1[8];

    uint kA0 = 0, kA1 = 0, kA2 = 0, kA3 = 0;
    uint kB0 = 0, kB1 = 0, kB2 = 0, kB3 = 0;
    float s1a = 0.f, s1b = 0.f;

#define CH4X(u16, idx, K0, K1, K2, K3, S1)                              \
    {                                                                   \
        uint uu = (uint)(u16);                                          \
        float vv = __uint_as_float(uu << 16);                           \
        S1 += __expf(fmaf(vv, INV_TAU, -INV_TAU));                      \
        uint od = uu ^ (0x8000u + (uu >> 15) * 0x7FFFu);                \
        uint nk = (od << 16) | (uint)(8191 - (idx));                    \
        uint q1 = med3u(nk, K0, K1);                                    \
        uint q2 = med3u(nk, K1, K2);                                    \
        uint q3 = med3u(nk, K2, K3);                                    \
        K0 = max(K0, nk); K1 = q1; K2 = q2; K3 = q3;                    \
    }
#define CH8(u16, idx)                                                   \
    {                                                                   \
        uint uu = (uint)(u16);                                          \
        uint od = uu ^ (0x8000u + (uu >> 15) * 0x7FFFu);                \
        uint nk = (od << 16) | (uint)(8191 - (idx));                    \
        uint q1 = med3u(nk, k0, k1);                                    \
        uint q2 = med3u(nk, k1, k2);                                    \
        uint q3 = med3u(nk, k2, k3);                                    \
        uint q4 = med3u(nk, k3, k4);                                    \
        uint q5 = med3u(nk, k4, k5);                                    \
        uint q6 = med3u(nk, k5, k6);                                    \
        uint q7 = med3u(nk, k6, k7);                                    \
        k0 = max(k0, nk);                                               \
        k1 = q1; k2 = q2; k3 = q3; k4 = q4; k5 = q5; k6 = q6; k7 = q7;  \
    }

    for (int i0 = base + lane * 8; i0 < base + 4096; i0 += 1024) {
        uint4 w = *(const uint4*)(row + i0);
        uint4 w2 = *(const uint4*)(row + i0 + 512);
        CH4X(w.x & 0xFFFF, i0 + 0, kA0, kA1, kA2, kA3, s1a);
        CH4X(w.x >> 16,    i0 + 1, kA0, kA1, kA2, kA3, s1a);
        CH4X(w.y & 0xFFFF, i0 + 2, kA0, kA1, kA2, kA3, s1a);
        CH4X(w.y >> 16,    i0 + 3, kA0, kA1, kA2, kA3, s1a);
        CH4X(w.z & 0xFFFF, i0 + 4, kA0, kA1, kA2, kA3, s1a);
        CH4X(w.z >> 16,    i0 + 5, kA0, kA1, kA2, kA3, s1a);
        CH4X(w.w & 0xFFFF, i0 + 6, kA0, kA1, kA2, kA3, s1a);
        CH4X(w.w >> 16,    i0 + 7, kA0, kA1, kA2, kA3, s1a);
        CH4X(w2.x & 0xFFFF, i0 + 512, kB0, kB1, kB2, kB3, s1b);
        CH4X(w2.x >> 16,    i0 + 513, kB0, kB1, kB2, kB3, s1b);
        CH4X(w2.y & 0xFFFF, i0 + 514, kB0, kB1, kB2, kB3, s1b);
        CH4X(w2.y >> 16,    i0 + 515, kB0, kB1, kB2, kB3, s1b);
        CH4X(w2.z & 0xFFFF, i0 + 516, kB0, kB1, kB2, kB3, s1b);
        CH4X(w2.z >> 16,    i0 + 517, kB0, kB1, kB2, kB3, s1b);
        CH4X(w2.w & 0xFFFF, i0 + 518, kB0, kB1, kB2, kB3, s1b);
        CH4X(w2.w >> 16,    i0 + 519, kB0, kB1, kB2, kB3, s1b);
    }
    // merge chains A,B -> per-lane top-4 (union merge network)
    uint k0 = max(kA0, kB0);
    uint k1 = max(max(min(kA0, kB0), kA1), kB1);
    uint k2 = max(max(min(kA0, kB1), min(kA1, kB0)), max(kA2, kB2));
    uint k3 = max(max(min(kA0, kB2), min(kA1, kB1)),
                  max(max(min(kA2, kB0), kA3), kB3));
    uint k4 = 0, k5 = 0, k6 = 0, k7 = 0;

    const uint prek3 = k3;   // >= max(kA3,kB3) >= every dropped element
#pragma unroll
    for (int d = 1; d < 64; d <<= 1) MERGESTEP(d)
    // exact iff every lane's dropped elems (<= its pre-merge k3) <= merged k7
    if (!__all((int)(prek3 <= k7))) {
        k0 = k1 = k2 = k3 = k4 = k5 = k6 = k7 = 0;
        for (int i0 = base + lane * 8; i0 < base + 4096; i0 += 512) {
            uint4 w = *(const uint4*)(row + i0);
            CH8(w.x & 0xFFFF, i0 + 0); CH8(w.x >> 16, i0 + 1);
            CH8(w.y & 0xFFFF, i0 + 2); CH8(w.y >> 16, i0 + 3);
            CH8(w.z & 0xFFFF, i0 + 4); CH8(w.z >> 16, i0 + 5);
            CH8(w.w & 0xFFFF, i0 + 6); CH8(w.w >> 16, i0 + 7);
        }
#pragma unroll
        for (int d = 1; d < 64; d <<= 1) MERGESTEP(d)
    }
#undef CH4X
#undef CH8

    // per-half s1 wave-reduce
    float s1 = s1a + s1b;
#pragma unroll
    for (int d = 1; d < 64; d <<= 1) s1 += __shfl_xor(s1, d);

    // ---- cross-wave merge via LDS ----
    if (lane == 0) {
        mk[wid][0] = k0; mk[wid][1] = k1; mk[wid][2] = k2; mk[wid][3] = k3;
        mk[wid][4] = k4; mk[wid][5] = k5; mk[wid][6] = k6; mk[wid][7] = k7;
        ms1[wid] = s1;
    }
    __syncthreads();
    if (half) return;                 // no further barriers below
    {
        const uint* q = mk[wid ^ 1];  // broadcast reads
        uint b0 = q[0], b1 = q[1], b2 = q[2], b3 = q[3];
        uint b4 = q[4], b5 = q[5], b6 = q[6], b7 = q[7];
        MERGEVALS
        s1 += ms1[wid ^ 1];
    }

    // ---- labels of top-8 ----
    const int l0 = labels[8191 - (int)(k0 & 0xFFFF)];
    const int l1 = labels[8191 - (int)(k1 & 0xFFFF)];
    const int l2 = labels[8191 - (int)(k2 & 0xFFFF)];
    const int l3 = labels[8191 - (int)(k3 & 0xFFFF)];
    const int l4 = labels[8191 - (int)(k4 & 0xFFFF)];
    const int l5 = labels[8191 - (int)(k5 & 0xFFFF)];
    const int l6 = labels[8191 - (int)(k6 & 0xFFFF)];
    const int l7 = labels[8191 - (int)(k7 & 0xFFFF)];

    // ---- assigned = min label among modes of top-5 labels ----
    const int c0 = 1 + (l0 == l1) + (l0 == l2) + (l0 == l3) + (l0 == l4);
    const int c1 = (l1 == l0) + 1 + (l1 == l2) + (l1 == l3) + (l1 == l4);
    const int c2 = (l2 == l0) + (l2 == l1) + 1 + (l2 == l3) + (l2 == l4);
    const int c3 = (l3 == l0) + (l3 == l1) + (l3 == l2) + 1 + (l3 == l4);
    const int c4 = (l4 == l0) + (l4 == l1) + (l4 == l2) + (l4 == l3) + 1;
    const int maxc = max(max(max(c0, c1), max(c2, c3)), c4);
    int assigned = 0x7fffffff;
    if (c0 == maxc) assigned = min(assigned, l0);
    if (c1 == maxc) assigned = min(assigned, l1);
    if (c2 == maxc) assigned = min(assigned, l2);
    if (c3 == maxc) assigned = min(assigned, l3);
    if (c4 == maxc) assigned = min(assigned, l4);
    const int aL = assigned;

    // ---- nun: first-4 negatives (exact if <=4 positives in top-8) ----
    const int negcnt = (l0 != aL) + (l1 != aL) + (l2 != aL) + (l3 != aL) +
                       (l4 != aL) + (l5 != aL) + (l6 != aL) + (l7 != aL);
    float nun = 0.f;
    if (negcnt >= 4) {
        int c = 0;
#define NSTEP(kj, lj)                                                       \
        {                                                                   \
            bool take = ((lj) != aL) && (c < 4);                            \
            nun += take ? ord2f((kj) >> 16) : 0.f;                          \
            c += take ? 1 : 0;                                              \
        }
        NSTEP(k0, l0) NSTEP(k1, l1) NSTEP(k2, l2) NSTEP(k3, l3)
        NSTEP(k4, l4) NSTEP(k5, l5) NSTEP(k6, l6) NSTEP(k7, l7)
#undef NSTEP
    } else {
        // rare fallback: full-row top-4 negative chain in ord domain
        uint n0 = 0, n1 = 0, n2 = 0, n3 = 0;
        for (int i0 = lane * 8; i0 < NSRC; i0 += 512) {
            uint4 w = *(const uint4*)(row + i0);
            uint2 lw = *(const uint2*)(lab8 + i0);
#define NEGP(u16, lb)                                                       \
            {                                                               \
                uint uu = (uint)(u16);                                      \
                uint od = uu ^ (0x8000u + (uu >> 15) * 0x7FFFu);            \
                uint x = ((lb) == aL) ? 0u : od;                            \
                uint q1 = med3u(x, n0, n1);                                 \
                uint q2 = med3u(x, n1, n2);                                 \
                uint q3 = med3u(x, n2, n3);                                 \
                n0 = max(n0, x); n1 = q1; n2 = q2; n3 = q3;                 \
            }
            NEGP(w.x & 0xFFFF, (int)(lw.x & 255));
            NEGP(w.x >> 16,    (int)((lw.x >> 8) & 255));
            NEGP(w.y & 0xFFFF, (int)((lw.x >> 16) & 255));
            NEGP(w.y >> 16,    (int)(lw.x >> 24));
            NEGP(w.z & 0xFFFF, (int)(lw.y & 255));
            NEGP(w.z >> 16,    (int)((lw.y >> 8) & 255));
            NEGP(w.w & 0xFFFF, (int)((lw.y >> 16) & 255));
            NEGP(w.w >> 16,    (int)(lw.y >> 24));
#undef NEGP
        }
#pragma unroll
        for (int d = 1; d < 64; d <<= 1) {
            uint b0 = __shfl_xor(n0, d), b1 = __shfl_xor(n1, d),
                 b2 = __shfl_xor(n2, d), b3 = __shfl_xor(n3, d);
            uint r0 = max(n0, b0);
            uint r1 = max(max(min(n0, b0), n1), b1);
            uint r2 = max(max(min(n0, b1), min(n1, b0)), max(n2, b2));
            uint r3 = max(max(min(n0, b2), min(n1, b1)),
                          max(max(min(n2, b0), n3), b3));
            n0 = r0; n1 = r1; n2 = r2; n3 = r3;
        }
        nun = (n0 ? ord2f(n0) : 0.f) + (n1 ? ord2f(n1) : 0.f) +
              (n2 ? ord2f(n2) : 0.f) + (n3 ? ord2f(n3) : 0.f);
    }

    // ---- class-member scan: top-4 positives + sp (gathered, ~128 elems) ----
    const int cs = cstart[aL], ce = cstart[aL + 1];
    float tp0 = -2.f, tp1 = -2.f, tp2 = -2.f, tp3 = -2.f;
    float sp = 0.f;
    for (int p = cs + lane; p < ce; p += 64) {
        const int idx = clist[p];
        float v = __uint_as_float(((uint)row[idx]) << 16);   // raw bf16 -> f32
        sp += __expf(fmaf(v, INV_TAU, -INV_TAU));
        float q1 = __builtin_amdgcn_fmed3f(v, tp0, tp1);
        float q2 = __builtin_amdgcn_fmed3f(v, tp1, tp2);
        float q3 = __builtin_amdgcn_fmed3f(v, tp2, tp3);
        tp0 = fmaxf(tp0, v); tp1 = q1; tp2 = q2; tp3 = q3;
    }
#pragma unroll
    for (int d = 1; d < 64; d <<= 1) {
        sp += __shfl_xor(sp, d);
        float b0 = __shfl_xor(tp0, d), b1 = __shfl_xor(tp1, d),
              b2 = __shfl_xor(tp2, d), b3 = __shfl_xor(tp3, d);
        float r0 = fmaxf(tp0, b0);
        float r1 = fmaxf(fmaxf(fminf(tp0, b0), tp1), b1);
        float r2 = fmaxf(fmaxf(fminf(tp0, b1), fminf(tp1, b0)), fmaxf(tp2, b2));
        float r3 = fmaxf(fmaxf(fminf(tp0, b2), fminf(tp1, b1)),
                         fmaxf(fmaxf(fminf(tp2, b0), tp3), b3));
        tp0 = r0; tp1 = r1; tp2 = r2; tp3 = r3;
    }

    if (lane == 0) {
        float nln = (tp0 > -1.5f ? tp0 : 0.f) + (tp1 > -1.5f ? tp1 : 0.f) +
                    (tp2 > -1.5f ? tp2 : 0.f) + (tp3 > -1.5f ? tp3 : 0.f);
        scores_out[t] = nln / nun;
        logt_out[t] = logf(sp / s1 + 1e-6f);
    }
}

// --------------------------------------- wave-per-element rank selection ----
__global__ __launch_bounds__(256) void select_topk_w(const float* __restrict__ scores,
                                                     int* __restrict__ selected,
                                                     int n, int k) {
    const int lane = threadIdx.x & 63, wid = threadIdx.x >> 6;
    const int t = blockIdx.x * 4 + wid;
    if (t >= n) return;
    const float st = scores[t];
    int rank = 0;
    for (int j0 = lane * 4; j0 < n; j0 += 256) {
        float4 v = *(const float4*)(scores + j0);
        rank += (v.x > st) || (v.x == st && (j0 + 0) < t);
        rank += (v.y > st) || (v.y == st && (j0 + 1) < t);
        rank += (v.z > st) || (v.z == st && (j0 + 2) < t);
        rank += (v.w > st) || (v.w == st && (j0 + 3) < t);
    }
    for (int d = 1; d < 64; d <<= 1) rank += __shfl_xor(rank, d);
    if (lane == 0) selected[t] = (rank < k) ? 1 : 0;
}

// ----------------------------------------------------------- finalize -------
__global__ __launch_bounds__(256) void finalize_k(const float* __restrict__ logt,
                                                  const int* __restrict__ selected,
                                                  float* __restrict__ out, int n, int k) {
    __shared__ float red[256];
    const int tid = threadIdx.x;
    float s = 0.f;
    for (int i = tid; i < n; i += 256) s += selected[i] ? logt[i] : 0.f;
    red[tid] = s;
    __syncthreads();
    for (int st = 128; st > 0; st >>= 1) {
        if (tid < st) red[tid] += red[tid + st];
        __syncthreads();
    }
    if (tid == 0) out[0] = -red[0] / (float)k;
}

// -------------------------------------------------------------- launch ------
extern "C" void kernel_launch(void* const* d_in, const int* in_sizes, int n_in,
                              void* d_out, int out_size, void* d_ws, size_t ws_size,
                              hipStream_t stream) {
    const float* srcF = (const float*)d_in[0];
    const int* labels = (const int*)d_in[1];
    const float* tgtF = (const float*)d_in[2];
    float* out = (float*)d_out;

    const int n_src = in_sizes[1];            // 8192
    const int d = in_sizes[0] / n_src;        // 256
    const int n_tgt = in_sizes[2] / d;        // 6144
    const int topn = n_tgt * 2 / 3;           // 4096

    char* ws = (char*)d_ws;
    ushort* src2 = (ushort*)ws;  ws += (size_t)n_src * DIM * sizeof(ushort);
    ushort* tgt2 = (ushort*)ws;  ws += (size_t)n_tgt * DIM * sizeof(ushort);
    ushort* sim  = (ushort*)ws;  ws += (size_t)n_tgt * NSRC * sizeof(ushort);
    float* scores = (float*)ws;  ws += (size_t)n_tgt * sizeof(float);
    float* logt   = (float*)ws;  ws += (size_t)n_tgt * sizeof(float);
    int* selected = (int*)ws;    ws += (size_t)n_tgt * sizeof(int);
    int* cstart   = (int*)ws;    ws += (size_t)(NCLS + 1) * sizeof(int);
    int* clist    = (int*)ws;    ws += (size_t)n_src * sizeof(int);
    uchar* lab8   = (uchar*)ws;  ws += (size_t)n_src;

    const int nrows = n_tgt + n_src;          // one wave per row, 4 waves/block
    l2bf2_k<<<(nrows + 3) / 4, 256, 0, stream>>>(tgtF, tgt2, n_tgt, srcF, src2, n_src);
    class_build_k<<<NCLS, 256, 0, stream>>>(labels, lab8, cstart, clist, n_src);

    dim3 grid(n_src / 128, n_tgt / 128);      // 64 x 48 = 3072 blocks
    gemm_mfma_k<<<grid, 512, 0, stream>>>(tgt2, src2, sim, n_tgt, n_src);

    assign_score_w<<<n_tgt / 4, 512, 0, stream>>>(sim, labels, lab8, cstart, clist,
                                                  scores, logt);
    select_topk_w<<<(n_tgt + 3) / 4, 256, 0, stream>>>(scores, selected, n_tgt, topn);
    finalize_k<<<1, 256, 0, stream>>>(logt, selected, out, n_tgt, topn);
}

// Round 14
// 108.572 us; speedup vs baseline: 1.0605x; 1.0604x over previous
//
#include <hip/hip_runtime.h>
#include <cstdint>
#include <cstddef>

#define DIM 256
#define NSRC 8192
#define NCLS 64
#define KSTEPS 8          // K=256 / 32
#define INV_TAU (1.0f / 0.07f)
#define EPITCH 136        // epilogue LDS pitch (ushorts): 272B rows, 16B-aligned

typedef __attribute__((ext_vector_type(8))) short bf16x8;
typedef __attribute__((ext_vector_type(4))) float f32x4;
typedef unsigned char uchar;

// ---------------------------------------------------------------- helpers ---
__device__ __forceinline__ ushort f2bf_rne(float f) {
    uint u = __float_as_uint(f);
    uint r = u + 0x7fff + ((u >> 16) & 1);
    return (ushort)(r >> 16);
}
// order-preserving bf16 -> u16 ordinal (monotone increasing with value)
__device__ __forceinline__ uint bf2ord(uint u) {
    return u ^ (0x8000u + (u >> 15) * 0x7FFFu);
}
__device__ __forceinline__ float ord2f(uint o) {
    uint u = (o & 0x8000u) ? (o ^ 0x8000u) : (~o & 0xFFFFu);
    return __uint_as_float(u << 16);
}
__device__ __forceinline__ uint med3u(uint a, uint b, uint c) {
    uint d;
    asm("v_med3_u32 %0, %1, %2, %3" : "=v"(d) : "v"(a), "v"(b), "v"(c));
    return d;
}

__device__ __forceinline__ void gload_lds16(const void* g, void* l) {
    __builtin_amdgcn_global_load_lds((const __attribute__((address_space(1))) void*)g,
                                     (__attribute__((address_space(3))) void*)l,
                                     16, 0, 0);
}

#define MERGESTEP(d)                                                               \
    {                                                                              \
        uint b0 = __shfl_xor(k0, d), b1 = __shfl_xor(k1, d), b2 = __shfl_xor(k2, d),\
             b3 = __shfl_xor(k3, d), b4 = __shfl_xor(k4, d), b5 = __shfl_xor(k5, d),\
             b6 = __shfl_xor(k6, d), b7 = __shfl_xor(k7, d);                        \
        uint r0 = max(k0, b0);                                                     \
        uint r1 = max(max(min(k0, b0), k1), b1);                                   \
        uint r2 = max(max(min(k0, b1), min(k1, b0)), max(k2, b2));                 \
        uint r3 = max(max(min(k0, b2), min(k1, b1)),                               \
                      max(max(min(k2, b0), k3), b3));                              \
        uint r4 = max(max(max(min(k0, b3), min(k1, b2)),                           \
                          max(min(k2, b1), min(k3, b0))), max(k4, b4));            \
        uint r5 = max(max(max(min(k0, b4), min(k1, b3)),                           \
                          max(min(k2, b2), min(k3, b1))),                          \
                      max(max(min(k4, b0), k5), b5));                              \
        uint r6 = max(max(max(min(k0, b5), min(k1, b4)),                           \
                          max(min(k2, b3), min(k3, b2))),                          \
                      max(max(min(k4, b1), min(k5, b0)), max(k6, b6)));            \
        uint r7 = max(max(max(min(k0, b6), min(k1, b5)),                           \
                          max(min(k2, b4), min(k3, b3))),                          \
                      max(max(min(k4, b2), min(k5, b1)),                           \
                          max(max(min(k6, b0), k7), b7)));                         \
        k0 = r0; k1 = r1; k2 = r2; k3 = r3; k4 = r4; k5 = r5; k6 = r6; k7 = r7;    \
    }

// ------------------------------------------------ l2norm -> bf16 (fused) ----
// one WAVE per row; waves [0, nA): A rows; [nA, nA+nB): B rows
__global__ __launch_bounds__(256) void l2bf2_k(const float* __restrict__ inA,
                                               ushort* __restrict__ outA, int nA,
                                               const float* __restrict__ inB,
                                               ushort* __restrict__ outB, int nB) {
    const int w = (blockIdx.x * 256 + threadIdx.x) >> 6;   // global wave id = row
    const int lane = threadIdx.x & 63;
    if (w >= nA + nB) return;
    const float* in;
    ushort* out;
    int row;
    if (w < nA) { in = inA; out = outA; row = w; }
    else        { in = inB; out = outB; row = w - nA; }
    float4 v = *(const float4*)(in + (size_t)row * DIM + lane * 4);
    float ss = v.x * v.x + v.y * v.y + v.z * v.z + v.w * v.w;
#pragma unroll
    for (int d = 1; d < 64; d <<= 1) ss += __shfl_xor(ss, d);
    const float n = fmaxf(sqrtf(ss), 1e-12f);
    ushort4 o;
    o.x = f2bf_rne(v.x / n);
    o.y = f2bf_rne(v.y / n);
    o.z = f2bf_rne(v.z / n);
    o.w = f2bf_rne(v.w / n);
    *(ushort4*)(out + (size_t)row * DIM + lane * 4) = o;
}

// ---------------- one-shot class build: lab8 + cstart + ordered clist -------
__global__ __launch_bounds__(256) void class_build_k(const int* __restrict__ labels,
                                                     uchar* __restrict__ lab8,
                                                     int* __restrict__ cstart,
                                                     int* __restrict__ clist, int n) {
    const int c = blockIdx.x, t = threadIdx.x;
    const int g = c * 256 + t;
    if (g < n) lab8[g] = (uchar)labels[g];

    __shared__ int sl[256], se[256];
    const int per = n >> 8;          // 32
    const int i0 = t * per;
    int less = 0, eq = 0;
    for (int j = 0; j < per; ++j) {
        const int l = labels[i0 + j];
        less += (l < c);
        eq += (l == c);
    }
    sl[t] = less; se[t] = eq;
    __syncthreads();
    for (int s = 1; s < 256; s <<= 1) {
        const int a = (t >= s) ? sl[t - s] : 0;
        const int b = (t >= s) ? se[t - s] : 0;
        __syncthreads();
        sl[t] += a; se[t] += b;
        __syncthreads();
    }
    const int base = sl[255];
    int pos = base + se[t] - eq;     // exclusive scan offset
    for (int j = 0; j < per; ++j) {
        const int i = i0 + j;
        if (labels[i] == c) clist[pos++] = i;
    }
    if (t == 0) cstart[c] = base;
    if (c == 0 && t == 1) cstart[NCLS] = n;
}

// ------------------------------------------------------------- MFMA GEMM ----
// C[M][N] (raw bf16) = A[M][256]*B[N][256]^T, 128x128 tile, 8 waves (512 thr).
// R9 EXACT (measured best, 40.4us): 3-deep 48KB ring + raw s_barrier +
// counted vmcnt + XCD-grouped mapping; each wave 32x64 (acc 2x4).
__global__ __launch_bounds__(512) void gemm_mfma_k(const ushort* __restrict__ A,
                                                   const ushort* __restrict__ B,
                                                   ushort* __restrict__ C,
                                                   int M, int N) {
    __shared__ __align__(16) ushort smem[24576];   // 48 KB

    const int tid = threadIdx.x;
    const int lane = tid & 63, wid = tid >> 6;
    const int wr = wid >> 1, wc = wid & 1;        // 4x2 waves, 32x64 each

    // XCD-aware 2D-grouped mapping: grid 64(bn) x 48(bm), 3072 blocks, 8 XCDs.
    const int gx = gridDim.x;                      // 64
    const int bid = blockIdx.y * gx + blockIdx.x;
    const int rowsPerX = gridDim.y >> 3;           // 6
    const int grpW = 8;
    const int grpSize = rowsPerX * grpW;           // 48
    const int xcd = bid & 7;
    const int local = bid >> 3;                    // 0..383
    const int grp = local / grpSize;
    const int within = local % grpSize;
    const int bm = (xcd * rowsPerX + within % rowsPerX) * 128;
    const int bn = (grp * grpW + within / rowsPerX) * 128;

    // ---- staging: chunk id = tid (0..511), one 16B chunk per matrix ----
    const int cr = tid >> 2;               // tile row 0..127
    const int cch = tid & 3;               // chunk within 64B row-slice
    const int sch = cch ^ ((cr >> 1) & 3); // swizzled source chunk
    const char* aSrcP = (const char*)A + (size_t)(bm + cr) * (DIM * 2) + sch * 16;
    const char* bSrcP = (const char*)B + (size_t)(bn + cr) * (DIM * 2) + sch * 16;
    const uint ldsOff = (uint)(wid * 1024);        // wave-uniform base; +lane*16

    const int fr = lane & 15, fk = lane >> 4;
    const int swz = (fr >> 1) & 3;
    int idxA[2], idxB[4];
#pragma unroll
    for (int m = 0; m < 2; ++m)
        idxA[m] = (wr * 32 + m * 16 + fr) * 32 + ((fk ^ swz) * 8);
#pragma unroll
    for (int n = 0; n < 4; ++n)
        idxB[n] = (wc * 64 + n * 16 + fr) * 32 + ((fk ^ swz) * 8);

    f32x4 acc[2][4];
#pragma unroll
    for (int m = 0; m < 2; ++m)
#pragma unroll
        for (int n = 0; n < 4; ++n) acc[m][n] = (f32x4){0.f, 0.f, 0.f, 0.f};

    // 2 loads/thread per STAGE (A chunk, B chunk); slot b in 0..2
#define STAGE(b, ks)                                                               \
    {                                                                              \
        gload_lds16(aSrcP + (ks) * 64, (char*)smem + (b) * 8192 + ldsOff);         \
        gload_lds16(bSrcP + (ks) * 64, (char*)smem + 24576 + (b) * 8192 + ldsOff); \
    }

    // prologue: 2 stages in flight (4 outstanding loads/thread)
    STAGE(0, 0);
    STAGE(1, 1);

#pragma unroll
    for (int ks = 0; ks < KSTEPS; ++ks) {
        if (ks < KSTEPS - 1) { asm volatile("s_waitcnt vmcnt(2)" ::: "memory"); }
        else                 { asm volatile("s_waitcnt vmcnt(0)" ::: "memory"); }
        __builtin_amdgcn_s_barrier();          // all waves' stage-ks loads landed
        asm volatile("" ::: "memory");         // no LDS read hoists above barrier

        if (ks + 2 < KSTEPS) STAGE((ks + 2) % 3, ks + 2);  // refill ring slot

        const int slot = ks % 3;
        const ushort* sAc = smem + slot * 4096;
        const ushort* sBc = smem + 12288 + slot * 4096;
        bf16x8 av[2], bv[4];
#pragma unroll
        for (int m = 0; m < 2; ++m) av[m] = *(const bf16x8*)&sAc[idxA[m]];
#pragma unroll
        for (int n = 0; n < 4; ++n) bv[n] = *(const bf16x8*)&sBc[idxB[n]];
#pragma unroll
        for (int m = 0; m < 2; ++m)
#pragma unroll
            for (int n = 0; n < 4; ++n)
                acc[m][n] = __builtin_amdgcn_mfma_f32_16x16x32_bf16(av[m], bv[n], acc[m][n], 0, 0, 0);
    }
#undef STAGE

    // ---- epilogue: fragments -> raw bf16 LDS tile -> coalesced 16B stores --
    __syncthreads();
#pragma unroll
    for (int m = 0; m < 2; ++m) {
#pragma unroll
        for (int n = 0; n < 4; ++n) {
            const int colb = wc * 64 + n * 16 + fr;
#pragma unroll
            for (int j = 0; j < 4; ++j) {
                const int rowb = wr * 32 + m * 16 + fk * 4 + j;
                smem[rowb * EPITCH + colb] = f2bf_rne(acc[m][n][j]);
            }
        }
    }
    __syncthreads();
    const int rr = tid >> 4, cc = (tid & 15) * 8;   // rr 0..31
#pragma unroll
    for (int it = 0; it < 4; ++it) {
        const int r = it * 32 + rr;
        uint4 v = *(const uint4*)&smem[r * EPITCH + cc];
        *(uint4*)(C + (size_t)(bm + r) * N + bn + cc) = v;
    }
}

// ---------------- wave-per-target: trimmed dual-chain scan ------------------
// sim holds RAW bf16. Keys: u32 = ord<<16 | (8191-idx) -> umax == (desc, idx asc)
// Op-trimmed scan: t = elem<<16 serves BOTH the s1 float and the 32-bit
// ordinal (ord32 = t ^ ((ashr(t,31)<<16)|0x80000000), low16 provably 0);
// index term folds to BK|(7-c) since 8191-i0 === 7 (mod 8) -- one or3 with
// an inline constant. Keys bit-identical to previous rounds.
__global__ __launch_bounds__(256) void assign_score_w(const ushort* __restrict__ sim,
                                                      const int* __restrict__ labels,
                                                      const uchar* __restrict__ lab8,
                                                      const int* __restrict__ cstart,
                                                      const int* __restrict__ clist,
                                                      float* __restrict__ scores_out,
                                                      float* __restrict__ logt_out) {
    const int lane = threadIdx.x & 63, wid = threadIdx.x >> 6;
    const int t = blockIdx.x * 4 + wid;
    const ushort* row = sim + (size_t)t * NSRC;

    uint kA0 = 0, kA1 = 0, kA2 = 0, kA3 = 0;
    uint kB0 = 0, kB1 = 0, kB2 = 0, kB3 = 0;
    float s1a = 0.f, s1b = 0.f;

#define INS4(nk, K0, K1, K2, K3)                                        \
    {                                                                   \
        uint q1 = med3u(nk, K0, K1);                                    \
        uint q2 = med3u(nk, K1, K2);                                    \
        uint q3 = med3u(nk, K2, K3);                                    \
        K0 = max(K0, nk); K1 = q1; K2 = q2; K3 = q3;                    \
    }
// process one 32-bit word (2 elems at c0, c0+1 within the 8-elem group)
#define CHW(w32, BK, C0, K0, K1, K2, K3, S1)                            \
    {                                                                   \
        uint tl = (w32) << 16;                                          \
        uint th = (w32) & 0xFFFF0000u;                                  \
        S1 += __expf(fmaf(__uint_as_float(tl), INV_TAU, -INV_TAU));     \
        S1 += __expf(fmaf(__uint_as_float(th), INV_TAU, -INV_TAU));     \
        uint ml = (uint)(((int)tl) >> 31);                              \
        uint mh = (uint)(((int)th) >> 31);                              \
        uint ol = tl ^ ((ml << 16) | 0x80000000u);                      \
        uint oh = th ^ ((mh << 16) | 0x80000000u);                      \
        uint nl = ol | (BK) | (uint)(7 - (C0));                         \
        uint nh = oh | (BK) | (uint)(6 - (C0));                         \
        INS4(nl, K0, K1, K2, K3);                                       \
        INS4(nh, K0, K1, K2, K3);                                       \
    }
#define CH8(u16, idx)                                                   \
    {                                                                   \
        uint uu = (uint)(u16);                                          \
        uint od = uu ^ (0x8000u + (uu >> 15) * 0x7FFFu);                \
        uint nk = (od << 16) | (uint)(8191 - (idx));                    \
        uint q1 = med3u(nk, k0, k1);                                    \
        uint q2 = med3u(nk, k1, k2);                                    \
        uint q3 = med3u(nk, k2, k3);                                    \
        uint q4 = med3u(nk, k3, k4);                                    \
        uint q5 = med3u(nk, k4, k5);                                    \
        uint q6 = med3u(nk, k5, k6);                                    \
        uint q7 = med3u(nk, k6, k7);                                    \
        k0 = max(k0, nk);                                               \
        k1 = q1; k2 = q2; k3 = q3; k4 = q4; k5 = q5; k6 = q6; k7 = q7;  \
    }

    for (int i0 = lane * 8; i0 < NSRC; i0 += 1024) {
        uint4 w = *(const uint4*)(row + i0);
        uint4 w2 = *(const uint4*)(row + i0 + 512);
        const uint bk1 = (uint)(8184 - i0);        // (8191-i0) & ~7
        const uint bk2 = (uint)(7672 - i0);        // (8191-i0-512) & ~7
        CHW(w.x, bk1, 0, kA0, kA1, kA2, kA3, s1a);
        CHW(w.y, bk1, 2, kA0, kA1, kA2, kA3, s1a);
        CHW(w.z, bk1, 4, kA0, kA1, kA2, kA3, s1a);
        CHW(w.w, bk1, 6, kA0, kA1, kA2, kA3, s1a);
        CHW(w2.x, bk2, 0, kB0, kB1, kB2, kB3, s1b);
        CHW(w2.y, bk2, 2, kB0, kB1, kB2, kB3, s1b);
        CHW(w2.z, bk2, 4, kB0, kB1, kB2, kB3, s1b);
        CHW(w2.w, bk2, 6, kB0, kB1, kB2, kB3, s1b);
    }
    // merge chains A,B -> per-lane top-4 (union merge network)
    uint k0 = max(kA0, kB0);
    uint k1 = max(max(min(kA0, kB0), kA1), kB1);
    uint k2 = max(max(min(kA0, kB1), min(kA1, kB0)), max(kA2, kB2));
    uint k3 = max(max(min(kA0, kB2), min(kA1, kB1)),
                  max(max(min(kA2, kB0), kA3), kB3));
    uint k4 = 0, k5 = 0, k6 = 0, k7 = 0;

    const uint prek3 = k3;   // >= max(kA3,kB3) >= every dropped element
#pragma unroll
    for (int d = 1; d < 64; d <<= 1) MERGESTEP(d)
    // exact iff every lane's dropped elems (<= its pre-merge k3) <= merged k7
    if (!__all((int)(prek3 <= k7))) {
        k0 = k1 = k2 = k3 = k4 = k5 = k6 = k7 = 0;
        for (int i0 = lane * 8; i0 < NSRC; i0 += 512) {
            uint4 w = *(const uint4*)(row + i0);
            CH8(w.x & 0xFFFF, i0 + 0); CH8(w.x >> 16, i0 + 1);
            CH8(w.y & 0xFFFF, i0 + 2); CH8(w.y >> 16, i0 + 3);
            CH8(w.z & 0xFFFF, i0 + 4); CH8(w.z >> 16, i0 + 5);
            CH8(w.w & 0xFFFF, i0 + 6); CH8(w.w >> 16, i0 + 7);
        }
#pragma unroll
        for (int d = 1; d < 64; d <<= 1) MERGESTEP(d)
    }
#undef CHW
#undef INS4
#undef CH8

    // s1 wave-reduce
    float s1 = s1a + s1b;
#pragma unroll
    for (int d = 1; d < 64; d <<= 1) s1 += __shfl_xor(s1, d);

    // ---- labels of top-8 ----
    const int l0 = labels[8191 - (int)(k0 & 0xFFFF)];
    const int l1 = labels[8191 - (int)(k1 & 0xFFFF)];
    const int l2 = labels[8191 - (int)(k2 & 0xFFFF)];
    const int l3 = labels[8191 - (int)(k3 & 0xFFFF)];
    const int l4 = labels[8191 - (int)(k4 & 0xFFFF)];
    const int l5 = labels[8191 - (int)(k5 & 0xFFFF)];
    const int l6 = labels[8191 - (int)(k6 & 0xFFFF)];
    const int l7 = labels[8191 - (int)(k7 & 0xFFFF)];

    // ---- assigned = min label among modes of top-5 labels ----
    const int c0 = 1 + (l0 == l1) + (l0 == l2) + (l0 == l3) + (l0 == l4);
    const int c1 = (l1 == l0) + 1 + (l1 == l2) + (l1 == l3) + (l1 == l4);
    const int c2 = (l2 == l0) + (l2 == l1) + 1 + (l2 == l3) + (l2 == l4);
    const int c3 = (l3 == l0) + (l3 == l1) + (l3 == l2) + 1 + (l3 == l4);
    const int c4 = (l4 == l0) + (l4 == l1) + (l4 == l2) + (l4 == l3) + 1;
    const int maxc = max(max(max(c0, c1), max(c2, c3)), c4);
    int assigned = 0x7fffffff;
    if (c0 == maxc) assigned = min(assigned, l0);
    if (c1 == maxc) assigned = min(assigned, l1);
    if (c2 == maxc) assigned = min(assigned, l2);
    if (c3 == maxc) assigned = min(assigned, l3);
    if (c4 == maxc) assigned = min(assigned, l4);
    const int aL = assigned;

    // ---- nun: first-4 negatives (exact if <=4 positives in top-8) ----
    const int negcnt = (l0 != aL) + (l1 != aL) + (l2 != aL) + (l3 != aL) +
                       (l4 != aL) + (l5 != aL) + (l6 != aL) + (l7 != aL);
    float nun = 0.f;
    if (negcnt >= 4) {
        int c = 0;
#define NSTEP(kj, lj)                                                       \
        {                                                                   \
            bool take = ((lj) != aL) && (c < 4);                            \
            nun += take ? ord2f((kj) >> 16) : 0.f;                          \
            c += take ? 1 : 0;                                              \
        }
        NSTEP(k0, l0) NSTEP(k1, l1) NSTEP(k2, l2) NSTEP(k3, l3)
        NSTEP(k4, l4) NSTEP(k5, l5) NSTEP(k6, l6) NSTEP(k7, l7)
#undef NSTEP
    } else {
        // rare fallback: full-row top-4 negative chain in ord domain
        uint n0 = 0, n1 = 0, n2 = 0, n3 = 0;
        for (int i0 = lane * 8; i0 < NSRC; i0 += 512) {
            uint4 w = *(const uint4*)(row + i0);
            uint2 lw = *(const uint2*)(lab8 + i0);
#define NEGP(u16, lb)                                                       \
            {                                                               \
                uint uu = (uint)(u16);                                      \
                uint od = uu ^ (0x8000u + (uu >> 15) * 0x7FFFu);            \
                uint x = ((lb) == aL) ? 0u : od;                            \
                uint q1 = med3u(x, n0, n1);                                 \
                uint q2 = med3u(x, n1, n2);                                 \
                uint q3 = med3u(x, n2, n3);                                 \
                n0 = max(n0, x); n1 = q1; n2 = q2; n3 = q3;                 \
            }
            NEGP(w.x & 0xFFFF, (int)(lw.x & 255));
            NEGP(w.x >> 16,    (int)((lw.x >> 8) & 255));
            NEGP(w.y & 0xFFFF, (int)((lw.x >> 16) & 255));
            NEGP(w.y >> 16,    (int)(lw.x >> 24));
            NEGP(w.z & 0xFFFF, (int)(lw.y & 255));
            NEGP(w.z >> 16,    (int)((lw.y >> 8) & 255));
            NEGP(w.w & 0xFFFF, (int)((lw.y >> 16) & 255));
            NEGP(w.w >> 16,    (int)(lw.y >> 24));
#undef NEGP
        }
#pragma unroll
        for (int d = 1; d < 64; d <<= 1) {
            uint b0 = __shfl_xor(n0, d), b1 = __shfl_xor(n1, d),
                 b2 = __shfl_xor(n2, d), b3 = __shfl_xor(n3, d);
            uint r0 = max(n0, b0);
            uint r1 = max(max(min(n0, b0), n1), b1);
            uint r2 = max(max(min(n0, b1), min(n1, b0)), max(n2, b2));
            uint r3 = max(max(min(n0, b2), min(n1, b1)),
                          max(max(min(n2, b0), n3), b3));
            n0 = r0; n1 = r1; n2 = r2; n3 = r3;
        }
        nun = (n0 ? ord2f(n0) : 0.f) + (n1 ? ord2f(n1) : 0.f) +
              (n2 ? ord2f(n2) : 0.f) + (n3 ? ord2f(n3) : 0.f);
    }

    // ---- class-member scan: top-4 positives + sp (gathered, ~128 elems) ----
    const int cs = cstart[aL], ce = cstart[aL + 1];
    float tp0 = -2.f, tp1 = -2.f, tp2 = -2.f, tp3 = -2.f;
    float sp = 0.f;
    for (int p = cs + lane; p < ce; p += 64) {
        const int idx = clist[p];
        float v = __uint_as_float(((uint)row[idx]) << 16);   // raw bf16 -> f32
        sp += __expf(fmaf(v, INV_TAU, -INV_TAU));
        float q1 = __builtin_amdgcn_fmed3f(v, tp0, tp1);
        float q2 = __builtin_amdgcn_fmed3f(v, tp1, tp2);
        float q3 = __builtin_amdgcn_fmed3f(v, tp2, tp3);
        tp0 = fmaxf(tp0, v); tp1 = q1; tp2 = q2; tp3 = q3;
    }
#pragma unroll
    for (int d = 1; d < 64; d <<= 1) {
        sp += __shfl_xor(sp, d);
        float b0 = __shfl_xor(tp0, d), b1 = __shfl_xor(tp1, d),
              b2 = __shfl_xor(tp2, d), b3 = __shfl_xor(tp3, d);
        float r0 = fmaxf(tp0, b0);
        float r1 = fmaxf(fmaxf(fminf(tp0, b0), tp1), b1);
        float r2 = fmaxf(fmaxf(fminf(tp0, b1), fminf(tp1, b0)), fmaxf(tp2, b2));
        float r3 = fmaxf(fmaxf(fminf(tp0, b2), fminf(tp1, b1)),
                         fmaxf(fmaxf(fminf(tp2, b0), tp3), b3));
        tp0 = r0; tp1 = r1; tp2 = r2; tp3 = r3;
    }

    if (lane == 0) {
        float nln = (tp0 > -1.5f ? tp0 : 0.f) + (tp1 > -1.5f ? tp1 : 0.f) +
                    (tp2 > -1.5f ? tp2 : 0.f) + (tp3 > -1.5f ? tp3 : 0.f);
        scores_out[t] = nln / nun;
        logt_out[t] = logf(sp / s1 + 1e-6f);
    }
}

// --------------------------------------- wave-per-element rank selection ----
__global__ __launch_bounds__(256) void select_topk_w(const float* __restrict__ scores,
                                                     int* __restrict__ selected,
                                                     int n, int k) {
    const int lane = threadIdx.x & 63, wid = threadIdx.x >> 6;
    const int t = blockIdx.x * 4 + wid;
    if (t >= n) return;
    const float st = scores[t];
    int rank = 0;
    for (int j0 = lane * 4; j0 < n; j0 += 256) {
        float4 v = *(const float4*)(scores + j0);
        rank += (v.x > st) || (v.x == st && (j0 + 0) < t);
        rank += (v.y > st) || (v.y == st && (j0 + 1) < t);
        rank += (v.z > st) || (v.z == st && (j0 + 2) < t);
        rank += (v.w > st) || (v.w == st && (j0 + 3) < t);
    }
    for (int d = 1; d < 64; d <<= 1) rank += __shfl_xor(rank, d);
    if (lane == 0) selected[t] = (rank < k) ? 1 : 0;
}

// ----------------------------------------------------------- finalize -------
__global__ __launch_bounds__(256) void finalize_k(const float* __restrict__ logt,
                                                  const int* __restrict__ selected,
                                                  float* __restrict__ out, int n, int k) {
    __shared__ float red[256];
    const int tid = threadIdx.x;
    float s = 0.f;
    for (int i = tid; i < n; i += 256) s += selected[i] ? logt[i] : 0.f;
    red[tid] = s;
    __syncthreads();
    for (int st = 128; st > 0; st >>= 1) {
        if (tid < st) red[tid] += red[tid + st];
        __syncthreads();
    }
    if (tid == 0) out[0] = -red[0] / (float)k;
}

// -------------------------------------------------------------- launch ------
extern "C" void kernel_launch(void* const* d_in, const int* in_sizes, int n_in,
                              void* d_out, int out_size, void* d_ws, size_t ws_size,
                              hipStream_t stream) {
    const float* srcF = (const float*)d_in[0];
    const int* labels = (const int*)d_in[1];
    const float* tgtF = (const float*)d_in[2];
    float* out = (float*)d_out;

    const int n_src = in_sizes[1];            // 8192
    const int d = in_sizes[0] / n_src;        // 256
    const int n_tgt = in_sizes[2] / d;        // 6144
    const int topn = n_tgt * 2 / 3;           // 4096

    char* ws = (char*)d_ws;
    ushort* src2 = (ushort*)ws;  ws += (size_t)n_src * DIM * sizeof(ushort);
    ushort* tgt2 = (ushort*)ws;  ws += (size_t)n_tgt * DIM * sizeof(ushort);
    ushort* sim  = (ushort*)ws;  ws += (size_t)n_tgt * NSRC * sizeof(ushort);
    float* scores = (float*)ws;  ws += (size_t)n_tgt * sizeof(float);
    float* logt   = (float*)ws;  ws += (size_t)n_tgt * sizeof(float);
    int* selected = (int*)ws;    ws += (size_t)n_tgt * sizeof(int);
    int* cstart   = (int*)ws;    ws += (size_t)(NCLS + 1) * sizeof(int);
    int* clist    = (int*)ws;    ws += (size_t)n_src * sizeof(int);
    uchar* lab8   = (uchar*)ws;  ws += (size_t)n_src;

    const int nrows = n_tgt + n_src;          // one wave per row, 4 waves/block
    l2bf2_k<<<(nrows + 3) / 4, 256, 0, stream>>>(tgtF, tgt2, n_tgt, srcF, src2, n_src);
    class_build_k<<<NCLS, 256, 0, stream>>>(labels, lab8, cstart, clist, n_src);

    dim3 grid(n_src / 128, n_tgt / 128);      // 64 x 48 = 3072 blocks
    gemm_mfma_k<<<grid, 512, 0, stream>>>(tgt2, src2, sim, n_tgt, n_src);

    assign_score_w<<<n_tgt / 4, 256, 0, stream>>>(sim, labels, lab8, cstart, clist,
                                                  scores, logt);
    select_topk_w<<<(n_tgt + 3) / 4, 256, 0, stream>>>(scores, selected, n_tgt, topn);
    finalize_k<<<1, 256, 0, stream>>>(logt, selected, out, n_tgt, topn);
}

// Round 15
// 108.277 us; speedup vs baseline: 1.0634x; 1.0027x over previous
//
#include <hip/hip_runtime.h>
#include <cstdint>
#include <cstddef>

#define DIM 256
#define NSRC 8192
#define NCLS 64
#define KSTEPS 8          // K=256 / 32
#define INV_TAU (1.0f / 0.07f)
#define EPITCH 136        // epilogue LDS pitch (ushorts): 272B rows, 16B-aligned

typedef __attribute__((ext_vector_type(8))) short bf16x8;
typedef __attribute__((ext_vector_type(4))) float f32x4;
typedef unsigned char uchar;

// ---------------------------------------------------------------- helpers ---
__device__ __forceinline__ ushort f2bf_rne(float f) {
    uint u = __float_as_uint(f);
    uint r = u + 0x7fff + ((u >> 16) & 1);
    return (ushort)(r >> 16);
}
// order-preserving bf16 -> u16 ordinal (monotone increasing with value)
__device__ __forceinline__ uint bf2ord(uint u) {
    return u ^ (0x8000u + (u >> 15) * 0x7FFFu);
}
__device__ __forceinline__ float ord2f(uint o) {
    uint u = (o & 0x8000u) ? (o ^ 0x8000u) : (~o & 0xFFFFu);
    return __uint_as_float(u << 16);
}
__device__ __forceinline__ uint med3u(uint a, uint b, uint c) {
    uint d;
    asm("v_med3_u32 %0, %1, %2, %3" : "=v"(d) : "v"(a), "v"(b), "v"(c));
    return d;
}

__device__ __forceinline__ void gload_lds16(const void* g, void* l) {
    __builtin_amdgcn_global_load_lds((const __attribute__((address_space(1))) void*)g,
                                     (__attribute__((address_space(3))) void*)l,
                                     16, 0, 0);
}

#define MERGESTEP(d)                                                               \
    {                                                                              \
        uint b0 = __shfl_xor(k0, d), b1 = __shfl_xor(k1, d), b2 = __shfl_xor(k2, d),\
             b3 = __shfl_xor(k3, d), b4 = __shfl_xor(k4, d), b5 = __shfl_xor(k5, d),\
             b6 = __shfl_xor(k6, d), b7 = __shfl_xor(k7, d);                        \
        uint r0 = max(k0, b0);                                                     \
        uint r1 = max(max(min(k0, b0), k1), b1);                                   \
        uint r2 = max(max(min(k0, b1), min(k1, b0)), max(k2, b2));                 \
        uint r3 = max(max(min(k0, b2), min(k1, b1)),                               \
                      max(max(min(k2, b0), k3), b3));                              \
        uint r4 = max(max(max(min(k0, b3), min(k1, b2)),                           \
                          max(min(k2, b1), min(k3, b0))), max(k4, b4));            \
        uint r5 = max(max(max(min(k0, b4), min(k1, b3)),                           \
                          max(min(k2, b2), min(k3, b1))),                          \
                      max(max(min(k4, b0), k5), b5));                              \
        uint r6 = max(max(max(min(k0, b5), min(k1, b4)),                           \
                          max(min(k2, b3), min(k3, b2))),                          \
                      max(max(min(k4, b1), min(k5, b0)), max(k6, b6)));            \
        uint r7 = max(max(max(min(k0, b6), min(k1, b5)),                           \
                          max(min(k2, b4), min(k3, b3))),                          \
                      max(max(min(k4, b2), min(k5, b1)),                           \
                          max(max(min(k6, b0), k7), b7)));                         \
        k0 = r0; k1 = r1; k2 = r2; k3 = r3; k4 = r4; k5 = r5; k6 = r6; k7 = r7;    \
    }

// ------------------- fused prep: l2norm->bf16 + class build -----------------
// blocks [0, nRowBlk): one WAVE per row (A rows then B rows).
// blocks [nRowBlk, nRowBlk+NCLS): class build, c = blockIdx.x - nRowBlk.
__global__ __launch_bounds__(256) void prep_k(const float* __restrict__ inA,
                                              ushort* __restrict__ outA, int nA,
                                              const float* __restrict__ inB,
                                              ushort* __restrict__ outB, int nB,
                                              const int* __restrict__ labels,
                                              uchar* __restrict__ lab8,
                                              int* __restrict__ cstart,
                                              int* __restrict__ clist, int n,
                                              int nRowBlk) {
    if ((int)blockIdx.x < nRowBlk) {
        const int w = (blockIdx.x * 256 + threadIdx.x) >> 6;   // global wave = row
        const int lane = threadIdx.x & 63;
        if (w >= nA + nB) return;
        const float* in;
        ushort* out;
        int row;
        if (w < nA) { in = inA; out = outA; row = w; }
        else        { in = inB; out = outB; row = w - nA; }
        float4 v = *(const float4*)(in + (size_t)row * DIM + lane * 4);
        float ss = v.x * v.x + v.y * v.y + v.z * v.z + v.w * v.w;
#pragma unroll
        for (int d = 1; d < 64; d <<= 1) ss += __shfl_xor(ss, d);
        const float nrm = fmaxf(sqrtf(ss), 1e-12f);
        ushort4 o;
        o.x = f2bf_rne(v.x / nrm);
        o.y = f2bf_rne(v.y / nrm);
        o.z = f2bf_rne(v.z / nrm);
        o.w = f2bf_rne(v.w / nrm);
        *(ushort4*)(out + (size_t)row * DIM + lane * 4) = o;
        return;
    }
    // ---- class build ----
    const int c = blockIdx.x - nRowBlk, t = threadIdx.x;
    const int g = c * 256 + t;
    if (g < n) lab8[g] = (uchar)labels[g];

    __shared__ int sl[256], se[256];
    const int per = n >> 8;          // 32
    const int i0 = t * per;
    int less = 0, eq = 0;
    for (int j = 0; j < per; ++j) {
        const int l = labels[i0 + j];
        less += (l < c);
        eq += (l == c);
    }
    sl[t] = less; se[t] = eq;
    __syncthreads();
    for (int s = 1; s < 256; s <<= 1) {
        const int a = (t >= s) ? sl[t - s] : 0;
        const int b = (t >= s) ? se[t - s] : 0;
        __syncthreads();
        sl[t] += a; se[t] += b;
        __syncthreads();
    }
    const int base = sl[255];
    int pos = base + se[t] - eq;     // exclusive scan offset
    for (int j = 0; j < per; ++j) {
        const int i = i0 + j;
        if (labels[i] == c) clist[pos++] = i;
    }
    if (t == 0) cstart[c] = base;
    if (c == 0 && t == 1) cstart[NCLS] = n;
}

// ------------------------------------------------------------- MFMA GEMM ----
// C[M][N] (raw bf16) = A[M][256]*B[N][256]^T, 128x128 tile, 8 waves (512 thr).
// R9 EXACT (measured best, 40.4us): 3-deep 48KB ring + raw s_barrier +
// counted vmcnt + XCD-grouped mapping; each wave 32x64 (acc 2x4).
// XCD x produces target rows [x*768, (x+1)*768) -- assign matches this.
__global__ __launch_bounds__(512) void gemm_mfma_k(const ushort* __restrict__ A,
                                                   const ushort* __restrict__ B,
                                                   ushort* __restrict__ C,
                                                   int M, int N) {
    __shared__ __align__(16) ushort smem[24576];   // 48 KB

    const int tid = threadIdx.x;
    const int lane = tid & 63, wid = tid >> 6;
    const int wr = wid >> 1, wc = wid & 1;        // 4x2 waves, 32x64 each

    // XCD-aware 2D-grouped mapping: grid 64(bn) x 48(bm), 3072 blocks, 8 XCDs.
    const int gx = gridDim.x;                      // 64
    const int bid = blockIdx.y * gx + blockIdx.x;
    const int rowsPerX = gridDim.y >> 3;           // 6
    const int grpW = 8;
    const int grpSize = rowsPerX * grpW;           // 48
    const int xcd = bid & 7;
    const int local = bid >> 3;                    // 0..383
    const int grp = local / grpSize;
    const int within = local % grpSize;
    const int bm = (xcd * rowsPerX + within % rowsPerX) * 128;
    const int bn = (grp * grpW + within / rowsPerX) * 128;

    // ---- staging: chunk id = tid (0..511), one 16B chunk per matrix ----
    const int cr = tid >> 2;               // tile row 0..127
    const int cch = tid & 3;               // chunk within 64B row-slice
    const int sch = cch ^ ((cr >> 1) & 3); // swizzled source chunk
    const char* aSrcP = (const char*)A + (size_t)(bm + cr) * (DIM * 2) + sch * 16;
    const char* bSrcP = (const char*)B + (size_t)(bn + cr) * (DIM * 2) + sch * 16;
    const uint ldsOff = (uint)(wid * 1024);        // wave-uniform base; +lane*16

    const int fr = lane & 15, fk = lane >> 4;
    const int swz = (fr >> 1) & 3;
    int idxA[2], idxB[4];
#pragma unroll
    for (int m = 0; m < 2; ++m)
        idxA[m] = (wr * 32 + m * 16 + fr) * 32 + ((fk ^ swz) * 8);
#pragma unroll
    for (int n = 0; n < 4; ++n)
        idxB[n] = (wc * 64 + n * 16 + fr) * 32 + ((fk ^ swz) * 8);

    f32x4 acc[2][4];
#pragma unroll
    for (int m = 0; m < 2; ++m)
#pragma unroll
        for (int n = 0; n < 4; ++n) acc[m][n] = (f32x4){0.f, 0.f, 0.f, 0.f};

    // 2 loads/thread per STAGE (A chunk, B chunk); slot b in 0..2
#define STAGE(b, ks)                                                               \
    {                                                                              \
        gload_lds16(aSrcP + (ks) * 64, (char*)smem + (b) * 8192 + ldsOff);         \
        gload_lds16(bSrcP + (ks) * 64, (char*)smem + 24576 + (b) * 8192 + ldsOff); \
    }

    // prologue: 2 stages in flight (4 outstanding loads/thread)
    STAGE(0, 0);
    STAGE(1, 1);

#pragma unroll
    for (int ks = 0; ks < KSTEPS; ++ks) {
        if (ks < KSTEPS - 1) { asm volatile("s_waitcnt vmcnt(2)" ::: "memory"); }
        else                 { asm volatile("s_waitcnt vmcnt(0)" ::: "memory"); }
        __builtin_amdgcn_s_barrier();          // all waves' stage-ks loads landed
        asm volatile("" ::: "memory");         // no LDS read hoists above barrier

        if (ks + 2 < KSTEPS) STAGE((ks + 2) % 3, ks + 2);  // refill ring slot

        const int slot = ks % 3;
        const ushort* sAc = smem + slot * 4096;
        const ushort* sBc = smem + 12288 + slot * 4096;
        bf16x8 av[2], bv[4];
#pragma unroll
        for (int m = 0; m < 2; ++m) av[m] = *(const bf16x8*)&sAc[idxA[m]];
#pragma unroll
        for (int n = 0; n < 4; ++n) bv[n] = *(const bf16x8*)&sBc[idxB[n]];
#pragma unroll
        for (int m = 0; m < 2; ++m)
#pragma unroll
            for (int n = 0; n < 4; ++n)
                acc[m][n] = __builtin_amdgcn_mfma_f32_16x16x32_bf16(av[m], bv[n], acc[m][n], 0, 0, 0);
    }
#undef STAGE

    // ---- epilogue: fragments -> raw bf16 LDS tile -> coalesced 16B stores --
    __syncthreads();
#pragma unroll
    for (int m = 0; m < 2; ++m) {
#pragma unroll
        for (int n = 0; n < 4; ++n) {
            const int colb = wc * 64 + n * 16 + fr;
#pragma unroll
            for (int j = 0; j < 4; ++j) {
                const int rowb = wr * 32 + m * 16 + fk * 4 + j;
                smem[rowb * EPITCH + colb] = f2bf_rne(acc[m][n][j]);
            }
        }
    }
    __syncthreads();
    const int rr = tid >> 4, cc = (tid & 15) * 8;   // rr 0..31
#pragma unroll
    for (int it = 0; it < 4; ++it) {
        const int r = it * 32 + rr;
        uint4 v = *(const uint4*)&smem[r * EPITCH + cc];
        *(uint4*)(C + (size_t)(bm + r) * N + bn + cc) = v;
    }
}

// ---------------- wave-per-target: trimmed dual-chain scan ------------------
// sim holds RAW bf16. Keys: u32 = ord<<16 | (8191-idx) -> umax == (desc, idx asc)
// XCD-affinity: block bid -> xcd = bid&7 consumes targets [xcd*768, ...) --
// the strip the SAME XCD's GEMM blocks produced (L2-warm sim rows).
__global__ __launch_bounds__(256) void assign_score_w(const ushort* __restrict__ sim,
                                                      const int* __restrict__ labels,
                                                      const uchar* __restrict__ lab8,
                                                      const int* __restrict__ cstart,
                                                      const int* __restrict__ clist,
                                                      float* __restrict__ scores_out,
                                                      float* __restrict__ logt_out) {
    const int lane = threadIdx.x & 63, wid = threadIdx.x >> 6;
    // producer-matched mapping: 1536 blocks, xcd=bid&7 owns 192 locals x 4
    const int t = (blockIdx.x & 7) * 768 + (blockIdx.x >> 3) * 4 + wid;
    const ushort* row = sim + (size_t)t * NSRC;

    uint kA0 = 0, kA1 = 0, kA2 = 0, kA3 = 0;
    uint kB0 = 0, kB1 = 0, kB2 = 0, kB3 = 0;
    float s1a = 0.f, s1b = 0.f;

#define INS4(nk, K0, K1, K2, K3)                                        \
    {                                                                   \
        uint q1 = med3u(nk, K0, K1);                                    \
        uint q2 = med3u(nk, K1, K2);                                    \
        uint q3 = med3u(nk, K2, K3);                                    \
        K0 = max(K0, nk); K1 = q1; K2 = q2; K3 = q3;                    \
    }
#define CHW(w32, BK, C0, K0, K1, K2, K3, S1)                            \
    {                                                                   \
        uint tl = (w32) << 16;                                          \
        uint th = (w32) & 0xFFFF0000u;                                  \
        S1 += __expf(fmaf(__uint_as_float(tl), INV_TAU, -INV_TAU));     \
        S1 += __expf(fmaf(__uint_as_float(th), INV_TAU, -INV_TAU));     \
        uint ml = (uint)(((int)tl) >> 31);                              \
        uint mh = (uint)(((int)th) >> 31);                              \
        uint ol = tl ^ ((ml << 16) | 0x80000000u);                      \
        uint oh = th ^ ((mh << 16) | 0x80000000u);                      \
        uint nl = ol | (BK) | (uint)(7 - (C0));                         \
        uint nh = oh | (BK) | (uint)(6 - (C0));                         \
        INS4(nl, K0, K1, K2, K3);                                       \
        INS4(nh, K0, K1, K2, K3);                                       \
    }
#define CH8(u16, idx)                                                   \
    {                                                                   \
        uint uu = (uint)(u16);                                          \
        uint od = uu ^ (0x8000u + (uu >> 15) * 0x7FFFu);                \
        uint nk = (od << 16) | (uint)(8191 - (idx));                    \
        uint q1 = med3u(nk, k0, k1);                                    \
        uint q2 = med3u(nk, k1, k2);                                    \
        uint q3 = med3u(nk, k2, k3);                                    \
        uint q4 = med3u(nk, k3, k4);                                    \
        uint q5 = med3u(nk, k4, k5);                                    \
        uint q6 = med3u(nk, k5, k6);                                    \
        uint q7 = med3u(nk, k6, k7);                                    \
        k0 = max(k0, nk);                                               \
        k1 = q1; k2 = q2; k3 = q3; k4 = q4; k5 = q5; k6 = q6; k7 = q7;  \
    }

    for (int i0 = lane * 8; i0 < NSRC; i0 += 1024) {
        uint4 w = *(const uint4*)(row + i0);
        uint4 w2 = *(const uint4*)(row + i0 + 512);
        const uint bk1 = (uint)(8184 - i0);        // (8191-i0) & ~7
        const uint bk2 = (uint)(7672 - i0);        // (8191-i0-512) & ~7
        CHW(w.x, bk1, 0, kA0, kA1, kA2, kA3, s1a);
        CHW(w.y, bk1, 2, kA0, kA1, kA2, kA3, s1a);
        CHW(w.z, bk1, 4, kA0, kA1, kA2, kA3, s1a);
        CHW(w.w, bk1, 6, kA0, kA1, kA2, kA3, s1a);
        CHW(w2.x, bk2, 0, kB0, kB1, kB2, kB3, s1b);
        CHW(w2.y, bk2, 2, kB0, kB1, kB2, kB3, s1b);
        CHW(w2.z, bk2, 4, kB0, kB1, kB2, kB3, s1b);
        CHW(w2.w, bk2, 6, kB0, kB1, kB2, kB3, s1b);
    }
    // merge chains A,B -> per-lane top-4 (union merge network)
    uint k0 = max(kA0, kB0);
    uint k1 = max(max(min(kA0, kB0), kA1), kB1);
    uint k2 = max(max(min(kA0, kB1), min(kA1, kB0)), max(kA2, kB2));
    uint k3 = max(max(min(kA0, kB2), min(kA1, kB1)),
                  max(max(min(kA2, kB0), kA3), kB3));
    uint k4 = 0, k5 = 0, k6 = 0, k7 = 0;

    const uint prek3 = k3;   // >= max(kA3,kB3) >= every dropped element
#pragma unroll
    for (int d = 1; d < 64; d <<= 1) MERGESTEP(d)
    // exact iff every lane's dropped elems (<= its pre-merge k3) <= merged k7
    if (!__all((int)(prek3 <= k7))) {
        k0 = k1 = k2 = k3 = k4 = k5 = k6 = k7 = 0;
        for (int i0 = lane * 8; i0 < NSRC; i0 += 512) {
            uint4 w = *(const uint4*)(row + i0);
            CH8(w.x & 0xFFFF, i0 + 0); CH8(w.x >> 16, i0 + 1);
            CH8(w.y & 0xFFFF, i0 + 2); CH8(w.y >> 16, i0 + 3);
            CH8(w.z & 0xFFFF, i0 + 4); CH8(w.z >> 16, i0 + 5);
            CH8(w.w & 0xFFFF, i0 + 6); CH8(w.w >> 16, i0 + 7);
        }
#pragma unroll
        for (int d = 1; d < 64; d <<= 1) MERGESTEP(d)
    }
#undef CHW
#undef INS4
#undef CH8

    // s1 wave-reduce
    float s1 = s1a + s1b;
#pragma unroll
    for (int d = 1; d < 64; d <<= 1) s1 += __shfl_xor(s1, d);

    // ---- labels of top-8 ----
    const int l0 = labels[8191 - (int)(k0 & 0xFFFF)];
    const int l1 = labels[8191 - (int)(k1 & 0xFFFF)];
    const int l2 = labels[8191 - (int)(k2 & 0xFFFF)];
    const int l3 = labels[8191 - (int)(k3 & 0xFFFF)];
    const int l4 = labels[8191 - (int)(k4 & 0xFFFF)];
    const int l5 = labels[8191 - (int)(k5 & 0xFFFF)];
    const int l6 = labels[8191 - (int)(k6 & 0xFFFF)];
    const int l7 = labels[8191 - (int)(k7 & 0xFFFF)];

    // ---- assigned = min label among modes of top-5 labels ----
    const int c0 = 1 + (l0 == l1) + (l0 == l2) + (l0 == l3) + (l0 == l4);
    const int c1 = (l1 == l0) + 1 + (l1 == l2) + (l1 == l3) + (l1 == l4);
    const int c2 = (l2 == l0) + (l2 == l1) + 1 + (l2 == l3) + (l2 == l4);
    const int c3 = (l3 == l0) + (l3 == l1) + (l3 == l2) + 1 + (l3 == l4);
    const int c4 = (l4 == l0) + (l4 == l1) + (l4 == l2) + (l4 == l3) + 1;
    const int maxc = max(max(max(c0, c1), max(c2, c3)), c4);
    int assigned = 0x7fffffff;
    if (c0 == maxc) assigned = min(assigned, l0);
    if (c1 == maxc) assigned = min(assigned, l1);
    if (c2 == maxc) assigned = min(assigned, l2);
    if (c3 == maxc) assigned = min(assigned, l3);
    if (c4 == maxc) assigned = min(assigned, l4);
    const int aL = assigned;

    // ---- nun: first-4 negatives (exact if <=4 positives in top-8) ----
    const int negcnt = (l0 != aL) + (l1 != aL) + (l2 != aL) + (l3 != aL) +
                       (l4 != aL) + (l5 != aL) + (l6 != aL) + (l7 != aL);
    float nun = 0.f;
    if (negcnt >= 4) {
        int c = 0;
#define NSTEP(kj, lj)                                                       \
        {                                                                   \
            bool take = ((lj) != aL) && (c < 4);                            \
            nun += take ? ord2f((kj) >> 16) : 0.f;                          \
            c += take ? 1 : 0;                                              \
        }
        NSTEP(k0, l0) NSTEP(k1, l1) NSTEP(k2, l2) NSTEP(k3, l3)
        NSTEP(k4, l4) NSTEP(k5, l5) NSTEP(k6, l6) NSTEP(k7, l7)
#undef NSTEP
    } else {
        // rare fallback: full-row top-4 negative chain in ord domain
        uint n0 = 0, n1 = 0, n2 = 0, n3 = 0;
        for (int i0 = lane * 8; i0 < NSRC; i0 += 512) {
            uint4 w = *(const uint4*)(row + i0);
            uint2 lw = *(const uint2*)(lab8 + i0);
#define NEGP(u16, lb)                                                       \
            {                                                               \
                uint uu = (uint)(u16);                                      \
                uint od = uu ^ (0x8000u + (uu >> 15) * 0x7FFFu);            \
                uint x = ((lb) == aL) ? 0u : od;                            \
                uint q1 = med3u(x, n0, n1);                                 \
                uint q2 = med3u(x, n1, n2);                                 \
                uint q3 = med3u(x, n2, n3);                                 \
                n0 = max(n0, x); n1 = q1; n2 = q2; n3 = q3;                 \
            }
            NEGP(w.x & 0xFFFF, (int)(lw.x & 255));
            NEGP(w.x >> 16,    (int)((lw.x >> 8) & 255));
            NEGP(w.y & 0xFFFF, (int)((lw.x >> 16) & 255));
            NEGP(w.y >> 16,    (int)(lw.x >> 24));
            NEGP(w.z & 0xFFFF, (int)(lw.y & 255));
            NEGP(w.z >> 16,    (int)((lw.y >> 8) & 255));
            NEGP(w.w & 0xFFFF, (int)((lw.y >> 16) & 255));
            NEGP(w.w >> 16,    (int)(lw.y >> 24));
#undef NEGP
        }
#pragma unroll
        for (int d = 1; d < 64; d <<= 1) {
            uint b0 = __shfl_xor(n0, d), b1 = __shfl_xor(n1, d),
                 b2 = __shfl_xor(n2, d), b3 = __shfl_xor(n3, d);
            uint r0 = max(n0, b0);
            uint r1 = max(max(min(n0, b0), n1), b1);
            uint r2 = max(max(min(n0, b1), min(n1, b0)), max(n2, b2));
            uint r3 = max(max(min(n0, b2), min(n1, b1)),
                          max(max(min(n2, b0), n3), b3));
            n0 = r0; n1 = r1; n2 = r2; n3 = r3;
        }
        nun = (n0 ? ord2f(n0) : 0.f) + (n1 ? ord2f(n1) : 0.f) +
              (n2 ? ord2f(n2) : 0.f) + (n3 ? ord2f(n3) : 0.f);
    }

    // ---- class-member scan: top-4 positives + sp (gathered, ~128 elems) ----
    const int cs = cstart[aL], ce = cstart[aL + 1];
    float tp0 = -2.f, tp1 = -2.f, tp2 = -2.f, tp3 = -2.f;
    float sp = 0.f;
    for (int p = cs + lane; p < ce; p += 64) {
        const int idx = clist[p];
        float v = __uint_as_float(((uint)row[idx]) << 16);   // raw bf16 -> f32
        sp += __expf(fmaf(v, INV_TAU, -INV_TAU));
        float q1 = __builtin_amdgcn_fmed3f(v, tp0, tp1);
        float q2 = __builtin_amdgcn_fmed3f(v, tp1, tp2);
        float q3 = __builtin_amdgcn_fmed3f(v, tp2, tp3);
        tp0 = fmaxf(tp0, v); tp1 = q1; tp2 = q2; tp3 = q3;
    }
#pragma unroll
    for (int d = 1; d < 64; d <<= 1) {
        sp += __shfl_xor(sp, d);
        float b0 = __shfl_xor(tp0, d), b1 = __shfl_xor(tp1, d),
              b2 = __shfl_xor(tp2, d), b3 = __shfl_xor(tp3, d);
        float r0 = fmaxf(tp0, b0);
        float r1 = fmaxf(fmaxf(fminf(tp0, b0), tp1), b1);
        float r2 = fmaxf(fmaxf(fminf(tp0, b1), fminf(tp1, b0)), fmaxf(tp2, b2));
        float r3 = fmaxf(fmaxf(fminf(tp0, b2), fminf(tp1, b1)),
                         fmaxf(fmaxf(fminf(tp2, b0), tp3), b3));
        tp0 = r0; tp1 = r1; tp2 = r2; tp3 = r3;
    }

    if (lane == 0) {
        float nln = (tp0 > -1.5f ? tp0 : 0.f) + (tp1 > -1.5f ? tp1 : 0.f) +
                    (tp2 > -1.5f ? tp2 : 0.f) + (tp3 > -1.5f ? tp3 : 0.f);
        scores_out[t] = nln / nun;
        logt_out[t] = logf(sp / s1 + 1e-6f);
    }
}

// --------------------------------------- wave-per-element rank selection ----
__global__ __launch_bounds__(256) void select_topk_w(const float* __restrict__ scores,
                                                     int* __restrict__ selected,
                                                     int n, int k) {
    const int lane = threadIdx.x & 63, wid = threadIdx.x >> 6;
    const int t = blockIdx.x * 4 + wid;
    if (t >= n) return;
    const float st = scores[t];
    int rank = 0;
    for (int j0 = lane * 4; j0 < n; j0 += 256) {
        float4 v = *(const float4*)(scores + j0);
        rank += (v.x > st) || (v.x == st && (j0 + 0) < t);
        rank += (v.y > st) || (v.y == st && (j0 + 1) < t);
        rank += (v.z > st) || (v.z == st && (j0 + 2) < t);
        rank += (v.w > st) || (v.w == st && (j0 + 3) < t);
    }
    for (int d = 1; d < 64; d <<= 1) rank += __shfl_xor(rank, d);
    if (lane == 0) selected[t] = (rank < k) ? 1 : 0;
}

// ----------------------------------------------------------- finalize -------
__global__ __launch_bounds__(256) void finalize_k(const float* __restrict__ logt,
                                                  const int* __restrict__ selected,
                                                  float* __restrict__ out, int n, int k) {
    __shared__ float red[256];
    const int tid = threadIdx.x;
    float s = 0.f;
    for (int i = tid; i < n; i += 256) s += selected[i] ? logt[i] : 0.f;
    red[tid] = s;
    __syncthreads();
    for (int st = 128; st > 0; st >>= 1) {
        if (tid < st) red[tid] += red[tid + st];
        __syncthreads();
    }
    if (tid == 0) out[0] = -red[0] / (float)k;
}

// -------------------------------------------------------------- launch ------
extern "C" void kernel_launch(void* const* d_in, const int* in_sizes, int n_in,
                              void* d_out, int out_size, void* d_ws, size_t ws_size,
                              hipStream_t stream) {
    const float* srcF = (const float*)d_in[0];
    const int* labels = (const int*)d_in[1];
    const float* tgtF = (const float*)d_in[2];
    float* out = (float*)d_out;

    const int n_src = in_sizes[1];            // 8192
    const int d = in_sizes[0] / n_src;        // 256
    const int n_tgt = in_sizes[2] / d;        // 6144
    const int topn = n_tgt * 2 / 3;           // 4096

    char* ws = (char*)d_ws;
    ushort* src2 = (ushort*)ws;  ws += (size_t)n_src * DIM * sizeof(ushort);
    ushort* tgt2 = (ushort*)ws;  ws += (size_t)n_tgt * DIM * sizeof(ushort);
    ushort* sim  = (ushort*)ws;  ws += (size_t)n_tgt * NSRC * sizeof(ushort);
    float* scores = (float*)ws;  ws += (size_t)n_tgt * sizeof(float);
    float* logt   = (float*)ws;  ws += (size_t)n_tgt * sizeof(float);
    int* selected = (int*)ws;    ws += (size_t)n_tgt * sizeof(int);
    int* cstart   = (int*)ws;    ws += (size_t)(NCLS + 1) * sizeof(int);
    int* clist    = (int*)ws;    ws += (size_t)n_src * sizeof(int);
    uchar* lab8   = (uchar*)ws;  ws += (size_t)n_src;

    const int nrows = n_tgt + n_src;              // one wave per row
    const int nRowBlk = (nrows + 3) / 4;          // 4 waves/block
    prep_k<<<nRowBlk + NCLS, 256, 0, stream>>>(tgtF, tgt2, n_tgt, srcF, src2, n_src,
                                               labels, lab8, cstart, clist, n_src,
                                               nRowBlk);

    dim3 grid(n_src / 128, n_tgt / 128);      // 64 x 48 = 3072 blocks
    gemm_mfma_k<<<grid, 512, 0, stream>>>(tgt2, src2, sim, n_tgt, n_src);

    assign_score_w<<<n_tgt / 4, 256, 0, stream>>>(sim, labels, lab8, cstart, clist,
                                                  scores, logt);
    select_topk_w<<<(n_tgt + 3) / 4, 256, 0, stream>>>(scores, selected, n_tgt, topn);
    finalize_k<<<1, 256, 0, stream>>>(logt, selected, out, n_tgt, topn);
}